// Round 9
// baseline (257.670 us; speedup 1.0000x reference)
//
#include <hip/hip_runtime.h>
#include <hip/hip_bf16.h>
#include <stdint.h>

typedef __bf16 bf16;
typedef __attribute__((ext_vector_type(8))) __bf16 bf16x8;
typedef __attribute__((ext_vector_type(4))) float f32x4;

#define DEVI __device__ __forceinline__

constexpr int Bz = 4, Sz = 2048, Dz = 512, Hz = 8, DKz = 64, DFFz = 2048;
constexpr int ROWSz = Bz * Sz;  // 8192
constexpr float EPSf = 1e-5f;
constexpr float C2f = 0.125f * 1.44269504088896f;  // 1/sqrt(DK) * log2(e)

// ---- async global->LDS, 16B per lane. LDS dest is wave-uniform base + lane*16.
DEVI void load_lds16(void* lds, const void* g) {
  __builtin_amdgcn_global_load_lds(
      (const __attribute__((address_space(1))) void*)(uintptr_t)(g),
      (__attribute__((address_space(3))) void*)(uint32_t)(uintptr_t)(lds),
      16, 0, 0);
}

// gfx950 cross-lane half-swaps (pure VALU; all lanes active in this kernel).
DEVI void permswap32(unsigned& x, unsigned& y) {
  asm("v_permlane32_swap_b32 %0, %1" : "+v"(x), "+v"(y));
}
DEVI void permswap16(unsigned& x, unsigned& y) {
  asm("v_permlane16_swap_b32 %0, %1" : "+v"(x), "+v"(y));
}

// =====================================================================
// GEMM (best measured mix, R11/R14):  C = A[M,K] @ Bt[N,K]^T  +bias.
// Used for QKV (EPI 3) and FFN1 (EPI 2).
// =====================================================================
template <int BM, int BK, int EPI>
__global__ __launch_bounds__(256, BM == 128 ? 4 : 3) void gemm_bt(
    const bf16* __restrict__ A, const bf16* __restrict__ Bt,
    const float* __restrict__ bias, const float* __restrict__ resid,
    const bf16* __restrict__ residb, bf16* __restrict__ aux,
    void* __restrict__ Cout, int M, int N, int K) {
  constexpr int BN = 128;
  constexpr int MI = BM / 32;          // m-frags per wave
  constexpr int RPI = 512 / BK;        // rows per 16B-issue (16 @BK32, 8 @BK64)
  constexpr int AISS = (BM / 4) / RPI; // A issues per wave
  constexpr int BISS = 32 / RPI;       // B issues per wave
  __shared__ alignas(16) bf16 sA[2][BM * BK];
  __shared__ alignas(16) bf16 sB[2][BN * BK];
  const int tid = threadIdx.x;
  const int lane = tid & 63;
  const int wv = tid >> 6;
  const int n0 = blockIdx.x * BN;
  const int m0 = blockIdx.y * BM;

  const int srow = (BK == 32) ? (lane >> 2) : (lane >> 3);
  const int sch = (BK == 32) ? (((lane & 3) ^ (srow & 3)) * 8)
                             : (((lane & 7) ^ (srow & 7)) * 8);
  const bf16* gA = A + (size_t)(m0 + wv * (BM / 4) + srow) * K + sch;
  const bf16* gB = Bt + (size_t)(n0 + wv * 32 + srow) * K + sch;

  const int wm = (wv >> 1) * (BM / 2);
  const int wn = (wv & 1) * 64;
  const int fr = lane & 15;
  const int fq = lane >> 4;

  auto stage = [&](int buf, int k0) {
#pragma unroll
    for (int j = 0; j < AISS; ++j)
      load_lds16(sA[buf] + (wv * (BM / 4) + j * RPI) * BK, gA + (size_t)(j * RPI) * K + k0);
#pragma unroll
    for (int j = 0; j < BISS; ++j)
      load_lds16(sB[buf] + (wv * 32 + j * RPI) * BK, gB + (size_t)(j * RPI) * K + k0);
  };

  f32x4 acc[MI][4] = {};

  stage(0, 0);
  __syncthreads();  // barrier's vmcnt(0) drain completes tile 0

  const int niter = K / BK;
  for (int it = 0; it < niter; ++it) {
    const int cur = it & 1;
    if (it + 1 < niter) stage(cur ^ 1, (it + 1) * BK);
#pragma unroll
    for (int kk = 0; kk < BK / 32; ++kk) {
      const int fc = (BK == 32) ? ((fq ^ (fr & 3)) * 8)
                                : (((4 * kk + fq) ^ (fr & 7)) * 8);
      bf16x8 af[MI], bfr[4];
#pragma unroll
      for (int i = 0; i < MI; ++i)
        af[i] = *(const bf16x8*)(sA[cur] + (wm + i * 16 + fr) * BK + fc);
#pragma unroll
      for (int j = 0; j < 4; ++j)
        bfr[j] = *(const bf16x8*)(sB[cur] + (wn + j * 16 + fr) * BK + fc);
#pragma unroll
      for (int i = 0; i < MI; ++i)
#pragma unroll
        for (int j = 0; j < 4; ++j)
          acc[i][j] = __builtin_amdgcn_mfma_f32_16x16x32_bf16(af[i], bfr[j], acc[i][j], 0, 0, 0);
    }
    __syncthreads();  // readers done with cur + prefetch DMA drained
  }

#pragma unroll
  for (int i = 0; i < MI; ++i) {
#pragma unroll
    for (int j = 0; j < 4; ++j) {
      const int col = n0 + wn + j * 16 + fr;
      const float bv = bias[col];
      if (EPI == 3 && col >= 1024) {
        const int row0 = m0 + wm + i * 16 + fq * 4;
        const int hh = (col - 1024) >> 6, dk = (col - 1024) & 63;
        const int bb = row0 >> 11, s0 = row0 & 2047;
        bf16 pv[4];
#pragma unroll
        for (int r = 0; r < 4; ++r) pv[r] = (bf16)(acc[i][j][r] + bv);
        *(uint2*)(aux + (size_t)((bb * 8 + hh) * 64 + dk) * 2048 + s0) = *(const uint2*)pv;
      } else {
#pragma unroll
        for (int r = 0; r < 4; ++r) {
          const int row = m0 + wm + i * 16 + fq * 4 + r;
          const size_t idx = (size_t)row * N + col;
          float v = acc[i][j][r] + bv;
          if (EPI == 1) {
            ((bf16*)Cout)[idx] = (bf16)(v + resid[idx]);
          } else if (EPI == 2) {
            ((bf16*)Cout)[idx] = (bf16)(v > 0.f ? v : 0.f);
          } else if (EPI == 3) {
            ((bf16*)Cout)[idx] = (bf16)(col < 512 ? v * C2f : v);
          } else {
            ((bf16*)Cout)[idx] = (bf16)(v + (float)residb[idx]);
          }
        }
      }
    }
  }
}

// =====================================================================
// Split-K GEMM (R9): C = A[M,K] @ Bt[N,K]^T + bias + bf16 resid.
// For the skinny-N tail GEMMs (Wo: 8192x512x512, FFN2: 8192x512x2048)
// whose grid (4x128=512 blocks of 256thr) was stuck at 2 blocks/CU =
// 8 waves/CU. Here: 512-thread blocks, 2 K-groups x 4 waves; group g
// computes K-range [g*K/2,(g+1)*K/2) with its own dbuf LDS tiles
// (BM=64/BK=32/BN=128, 48KB union); group 0 stores acc to LDS
// (stride-33 pad: (33l+k)%32=(l+k)%32 -> 2-lane/bank = free), group 1
// adds + writes epilogue. Exact fp32 merge. Same grid -> 16 waves/CU
// = 4 waves/SIMD (2x), K-depth per wave halved.
// Staging/swizzle math byte-identical to gemm_bt BK=32 path
// (pre-swizzled global source -> linear LDS; read fc unchanged).
// =====================================================================
__global__ __launch_bounds__(512, 4) void gemm_bt_sk(
    const bf16* __restrict__ A, const bf16* __restrict__ Bt,
    const float* __restrict__ bias, const bf16* __restrict__ residb,
    bf16* __restrict__ Cout, int M, int N, int K) {
  constexpr int BM = 64, BK = 32, BN = 128;
  constexpr int MI = 2;
  __shared__ alignas(16) union SM {
    struct { bf16 a[2][2][BM * BK]; bf16 b[2][2][BN * BK]; } t;  // [group][buf]
    float mrg[4][64][33];  // [wg][lane][32 acc + pad]
  } sm;
  const int tid = threadIdx.x, lane = tid & 63, wv = tid >> 6;
  const int g = wv >> 2;   // K-group
  const int wg = wv & 3;   // wave in group
  const int n0 = blockIdx.x * BN;
  const int m0 = blockIdx.y * BM;
  const int kbase = g * (K >> 1);

  const int srow = lane >> 2;                     // 0..15
  const int sch = ((lane & 3) ^ (srow & 3)) * 8;  // pre-swizzled source chunk
  const bf16* gA = A + (size_t)(m0 + wg * 16 + srow) * K + kbase + sch;
  const bf16* gB = Bt + (size_t)(n0 + wg * 32 + srow) * K + kbase + sch;

  const int wm = (wg >> 1) * 32;
  const int wn = (wg & 1) * 64;
  const int fr = lane & 15;
  const int fq = lane >> 4;

  auto stage = [&](int buf, int k0) {
    load_lds16(sm.t.a[g][buf] + (wg * 16) * BK, gA + k0);
    load_lds16(sm.t.b[g][buf] + (wg * 32) * BK, gB + k0);
    load_lds16(sm.t.b[g][buf] + (wg * 32 + 16) * BK, gB + (size_t)16 * K + k0);
  };

  f32x4 acc[MI][4] = {};

  stage(0, 0);
  __syncthreads();

  const int niter = (K >> 1) / BK;  // 8 for Wo, 32 for FFN2
  for (int it = 0; it < niter; ++it) {
    const int cur = it & 1;
    if (it + 1 < niter) stage(cur ^ 1, (it + 1) * BK);
    const int fc = (fq ^ (fr & 3)) * 8;
    bf16x8 af[MI], bfr[4];
#pragma unroll
    for (int i = 0; i < MI; ++i)
      af[i] = *(const bf16x8*)(sm.t.a[g][cur] + (wm + i * 16 + fr) * BK + fc);
#pragma unroll
    for (int j = 0; j < 4; ++j)
      bfr[j] = *(const bf16x8*)(sm.t.b[g][cur] + (wn + j * 16 + fr) * BK + fc);
#pragma unroll
    for (int i = 0; i < MI; ++i)
#pragma unroll
      for (int j = 0; j < 4; ++j)
        acc[i][j] = __builtin_amdgcn_mfma_f32_16x16x32_bf16(af[i], bfr[j], acc[i][j], 0, 0, 0);
    __syncthreads();  // readers done + prefetch DMA drained (incl. last iter)
  }

  // ---- K-merge: group 0 -> LDS (tiles dead; barrier-protected), group 1 adds.
  if (g == 0) {
    float* mp = sm.mrg[wg][lane];
#pragma unroll
    for (int i = 0; i < MI; ++i)
#pragma unroll
      for (int j = 0; j < 4; ++j)
#pragma unroll
        for (int r = 0; r < 4; ++r) mp[i * 16 + j * 4 + r] = acc[i][j][r];
  }
  __syncthreads();
  if (g == 1) {
    const float* mp = sm.mrg[wg][lane];
#pragma unroll
    for (int i = 0; i < MI; ++i)
#pragma unroll
      for (int j = 0; j < 4; ++j) {
        const int col = n0 + wn + j * 16 + fr;
        const float bv = bias[col];
#pragma unroll
        for (int r = 0; r < 4; ++r) {
          const int row = m0 + wm + i * 16 + fq * 4 + r;
          const size_t idx = (size_t)row * N + col;
          float v = acc[i][j][r] + mp[i * 16 + j * 4 + r] + bv;
          Cout[idx] = (bf16)(v + (float)residb[idx]);
        }
      }
  }
}

// =====================================================================
// Flash attention v8 (R8, frozen): t-split + 32 q-rows/wave, 50.0us.
// 8-wave blocks: waves 0-3 tiles 0-15, waves 4-7 tiles 16-31, same
// 128 q-rows; partials merged via LDS (max-free softmax => pure sums).
// Grid 512, 16 waves/CU = 4/SIMD. MfmaUtil 26% = exactly algorithmic
// MFMA content; further gains need full HK 4-cluster co-design.
// =====================================================================
__global__ __launch_bounds__(512, 4) void flash_attn(
    const bf16* __restrict__ qkv, const bf16* __restrict__ Vt,
    bf16* __restrict__ ctx) {
  const int bid = blockIdx.x;
  const int qt = bid >> 5;         // 0..15, 128-row q tiles
  const int bh = bid & 31;         // bid%8 == h -> XCD pinning per head
  const int h = bh & 7;
  const int b = bh >> 3;
  const int q0 = qt * 128;
  const int tid = threadIdx.x, lane = tid & 63, wv = tid >> 6;  // wv 0..7
  const int g = wv >> 2;           // t-group: 0 -> tiles 0..15, 1 -> 16..31
  const int wg = wv & 3;           // wave in group; owns q rows wg*32..+31
  const int fr = lane & 15, fq = lane >> 4;
  const int xsw = fr & 7;

  __shared__ alignas(16) union SMem {
    struct { bf16 K[2][2][64 * 64]; bf16 V[2][2][64 * 64]; } kv;
    float mrg[4 * 64 * 35];  // 4 waves x 64 lanes x (32 acc + 2 l + pad)
  } sm;

  const int srow = lane >> 3;                // 0..7 within 8-row issue
  const int scol = ((lane & 7) ^ srow) * 8;  // swizzled chunk (elements)

  const bf16* gK = qkv + (size_t)(b * Sz + wg * 16 + srow) * 1536 + 512 + h * 64 + scol;
  const bf16* gV = Vt + (size_t)((b * 8 + h) * 64 + wg * 16 + srow) * Sz + scol;

  auto stage = [&](int p, int t) {
    const size_t t0 = (size_t)t * 64;
    load_lds16(sm.kv.K[g][p] + (wg * 16 + 0) * 64, gK + t0 * 1536);
    load_lds16(sm.kv.K[g][p] + (wg * 16 + 8) * 64, gK + (t0 + 8) * 1536);
    load_lds16(sm.kv.V[g][p] + (wg * 16 + 0) * 64, gV + t0);
    load_lds16(sm.kv.V[g][p] + (wg * 16 + 8) * 64, gV + (size_t)8 * Sz + t0);
  };

  stage(0, g * 16);  // tile 0 of own range

  const bf16* gQf = qkv + (size_t)(b * Sz + q0 + wg * 32 + fr) * 1536 + h * 64;
  bf16x8 qb[2][2];
  qb[0][0] = *(const bf16x8*)(gQf + fq * 8);
  qb[0][1] = *(const bf16x8*)(gQf + (fq + 4) * 8);
  qb[1][0] = *(const bf16x8*)(gQf + (size_t)16 * 1536 + fq * 8);
  qb[1][1] = *(const bf16x8*)(gQf + (size_t)16 * 1536 + (fq + 4) * 8);

  asm volatile("s_waitcnt vmcnt(0)" ::: "memory");  // qb + stage(0) landed
  __builtin_amdgcn_s_barrier();
  asm volatile("" ::: "memory");

  const int colc0 = (fq ^ xsw) * 8;
  const int colc1 = ((fq + 4) ^ xsw) * 8;
  int qsrc[4];
#pragma unroll
  for (int r = 0; r < 4; ++r) qsrc[r] = (fq * 4 + r) | (lane & 48);

  const f32x4 ZERO = {0.f, 0.f, 0.f, 0.f};
  float l_part[2] = {0.f, 0.f};
  f32x4 acc_o[2][4] = {};

  for (int st = 0; st < 16; ++st) {
    const int p = st & 1;
    if (st + 1 < 16) stage(p ^ 1, g * 16 + st + 1);

    const bf16* kb = sm.kv.K[g][p];
    const bf16* vb = sm.kv.V[g][p];

    bf16x8 kf[2][4];
#pragma unroll
    for (int j = 0; j < 4; ++j) {
      kf[0][j] = *(const bf16x8*)(kb + (j * 16 + fr) * 64 + colc0);
      kf[1][j] = *(const bf16x8*)(kb + (j * 16 + fr) * 64 + colc1);
    }
    f32x4 sc[2][4];
    __builtin_amdgcn_s_setprio(1);
#pragma unroll
    for (int s = 0; s < 2; ++s)
#pragma unroll
      for (int j = 0; j < 4; ++j) {
        f32x4 z = __builtin_amdgcn_mfma_f32_16x16x32_bf16(kf[0][j], qb[s][0], ZERO, 0, 0, 0);
        sc[s][j] = __builtin_amdgcn_mfma_f32_16x16x32_bf16(kf[1][j], qb[s][1], z, 0, 0, 0);
      }
    __builtin_amdgcn_s_setprio(0);

    bf16x8 pa[2][2];
#pragma unroll
    for (int s = 0; s < 2; ++s) {
      unsigned c0[4], c1[4];
      float rs = 0.f;
#pragma unroll
      for (int j = 0; j < 4; ++j) {
        float e0 = __builtin_amdgcn_exp2f(sc[s][j][0]);
        float e1 = __builtin_amdgcn_exp2f(sc[s][j][1]);
        float e2 = __builtin_amdgcn_exp2f(sc[s][j][2]);
        float e3 = __builtin_amdgcn_exp2f(sc[s][j][3]);
        rs += (e0 + e1) + (e2 + e3);
        union { bf16 hh[2]; unsigned u; } pka, pkb;
        pka.hh[0] = (bf16)e0; pka.hh[1] = (bf16)e1;  // v_cvt_pk_bf16_f32
        pkb.hh[0] = (bf16)e2; pkb.hh[1] = (bf16)e3;
        c0[j] = pka.u;
        c1[j] = pkb.u;
      }
      l_part[s] += rs;
#pragma unroll
      for (int kk = 0; kk < 2; ++kk) {
        unsigned x0 = c0[2 * kk], y0 = c0[2 * kk + 1];
        permswap32(x0, y0);
        permswap16(x0, y0);
        unsigned x1 = c1[2 * kk], y1 = c1[2 * kk + 1];
        permswap32(x1, y1);
        permswap16(x1, y1);
        union { unsigned u[4]; bf16x8 v; } pk;
        pk.u[0] = x0; pk.u[1] = x1; pk.u[2] = y0; pk.u[3] = y1;
        pa[s][kk] = pk.v;
      }
    }

    bf16x8 vf[2][4];
#pragma unroll
    for (int j = 0; j < 4; ++j) {
      vf[0][j] = *(const bf16x8*)(vb + (j * 16 + fr) * 64 + colc0);
      vf[1][j] = *(const bf16x8*)(vb + (j * 16 + fr) * 64 + colc1);
    }
    __builtin_amdgcn_s_setprio(1);
#pragma unroll
    for (int s = 0; s < 2; ++s)
#pragma unroll
      for (int kk = 0; kk < 2; ++kk)
#pragma unroll
        for (int j = 0; j < 4; ++j)
          acc_o[s][j] = __builtin_amdgcn_mfma_f32_16x16x32_bf16(pa[s][kk], vf[kk][j], acc_o[s][j], 0, 0, 0);
    __builtin_amdgcn_s_setprio(0);

    if (st + 1 < 16) {
      asm volatile("s_waitcnt vmcnt(0)" ::: "memory");  // own stage landed
      __builtin_amdgcn_s_barrier();
      asm volatile("" ::: "memory");
    }
  }

  // ---- t-split merge: A's partials -> LDS (aliases K/V, dead now); B adds.
  __syncthreads();  // all waves done computing before mrg overwrites K/V
  if (g == 0) {
    float* mp = sm.mrg + (wg * 64 + lane) * 35;
#pragma unroll
    for (int s = 0; s < 2; ++s)
#pragma unroll
      for (int j = 0; j < 4; ++j)
#pragma unroll
        for (int r = 0; r < 4; ++r) mp[s * 16 + j * 4 + r] = acc_o[s][j][r];
    mp[32] = l_part[0];
    mp[33] = l_part[1];
  }
  __syncthreads();
  if (g == 1) {
    const float* mp = sm.mrg + (wg * 64 + lane) * 35;
#pragma unroll
    for (int s = 0; s < 2; ++s)
#pragma unroll
      for (int j = 0; j < 4; ++j)
#pragma unroll
        for (int r = 0; r < 4; ++r) acc_o[s][j][r] += mp[s * 16 + j * 4 + r];
    l_part[0] += mp[32];
    l_part[1] += mp[33];

#pragma unroll
    for (int s = 0; s < 2; ++s) {
      float l = l_part[s];
      l += __shfl_xor(l, 16, 64);
      l += __shfl_xor(l, 32, 64);
      float rl[4];
#pragma unroll
      for (int r = 0; r < 4; ++r) rl[r] = 1.0f / __shfl(l, qsrc[r], 64);
#pragma unroll
      for (int j = 0; j < 4; ++j)
#pragma unroll
        for (int r = 0; r < 4; ++r) {
          const int row = b * Sz + q0 + wg * 32 + s * 16 + fq * 4 + r;
          const int col = h * 64 + j * 16 + fr;
          ctx[(size_t)row * Dz + col] = (bf16)(acc_o[s][j][r] * rl[r]);
        }
    }
  }
}

// =====================================================================
// LayerNorm: one wave per row of 512. bf16 input; fp32 or bf16 output.
// =====================================================================
template <int OUT_F32>
__global__ __launch_bounds__(256) void layer_norm_k(
    const bf16* __restrict__ y, const float* __restrict__ g,
    const float* __restrict__ be, void* __restrict__ out) {
  const int row = blockIdx.x * 4 + (threadIdx.x >> 6);
  const int lane = threadIdx.x & 63;
  const int col = lane * 8;
  bf16x8 hv = *(const bf16x8*)(y + (size_t)row * Dz + col);
  float v[8];
  float s = 0.f, ss = 0.f;
#pragma unroll
  for (int i = 0; i < 8; ++i) {
    v[i] = (float)hv[i];
    s += v[i];
    ss += v[i] * v[i];
  }
#pragma unroll
  for (int o = 1; o < 64; o <<= 1) {
    s += __shfl_xor(s, o, 64);
    ss += __shfl_xor(ss, o, 64);
  }
  const float mu = s * (1.0f / Dz);
  const float rstd = rsqrtf(ss * (1.0f / Dz) - mu * mu + EPSf);
  const float4* g4 = (const float4*)(g + col);
  const float4* b4 = (const float4*)(be + col);
  float4 ga = g4[0], gb = g4[1], ba = b4[0], bb = b4[1];
  float o8[8];
  o8[0] = (v[0] - mu) * rstd * ga.x + ba.x;
  o8[1] = (v[1] - mu) * rstd * ga.y + ba.y;
  o8[2] = (v[2] - mu) * rstd * ga.z + ba.z;
  o8[3] = (v[3] - mu) * rstd * ga.w + ba.w;
  o8[4] = (v[4] - mu) * rstd * gb.x + bb.x;
  o8[5] = (v[5] - mu) * rstd * gb.y + bb.y;
  o8[6] = (v[6] - mu) * rstd * gb.z + bb.z;
  o8[7] = (v[7] - mu) * rstd * gb.w + bb.w;
  if (OUT_F32) {
    float4* of = (float4*)((float*)out + (size_t)row * Dz + col);
    of[0] = make_float4(o8[0], o8[1], o8[2], o8[3]);
    of[1] = make_float4(o8[4], o8[5], o8[6], o8[7]);
  } else {
    bf16 ob[8];
#pragma unroll
    for (int i = 0; i < 8; ++i) ob[i] = (bf16)o8[i];
    *(uint4*)((bf16*)out + (size_t)row * Dz + col) = *(const uint4*)ob;
  }
}

// =====================================================================
// Fused prep: all 6 weight transposes (fp32[K,N] -> bf16[N,K], 64x64
// tiles), bias concat, x -> bf16 cast. One launch.
// =====================================================================
__global__ __launch_bounds__(256) void prep_all(
    const float* __restrict__ Wq, const float* __restrict__ Wk,
    const float* __restrict__ Wv, const float* __restrict__ Wo,
    const float* __restrict__ W1, const float* __restrict__ W2,
    const float* __restrict__ bq, const float* __restrict__ bk,
    const float* __restrict__ bv, const float* __restrict__ x,
    bf16* __restrict__ WqkvT, bf16* __restrict__ WoT,
    bf16* __restrict__ W1T, bf16* __restrict__ W2T,
    float* __restrict__ bqkv, bf16* __restrict__ xb) {
  __shared__ float tile[64][65];
  const int blk = blockIdx.x;
  const int t = threadIdx.x;
  if (blk < 768) {
    const float* W;
    bf16* Wt;
    int K, N, local;
    if (blk < 64)       { W = Wq; Wt = WqkvT;                       K = 512;  N = 512;  local = blk; }
    else if (blk < 128) { W = Wk; Wt = WqkvT + (size_t)512 * 512;   K = 512;  N = 512;  local = blk - 64; }
    else if (blk < 192) { W = Wv; Wt = WqkvT + (size_t)1024 * 512;  K = 512;  N = 512;  local = blk - 128; }
    else if (blk < 256) { W = Wo; Wt = WoT;                         K = 512;  N = 512;  local = blk - 192; }
    else if (blk < 512) { W = W1; Wt = W1T;                         K = 512;  N = 2048; local = blk - 256; }
    else                { W = W2; Wt = W2T;                         K = 2048; N = 512;  local = blk - 512; }
    const int kt = K / 64;
    const int k0 = (local % kt) * 64, n0 = (local / kt) * 64;
    const int r = t >> 2, c = (t & 3) * 16;
    const float* src = W + (size_t)(k0 + r) * N + n0 + c;
#pragma unroll
    for (int i = 0; i < 4; ++i) {
      float4 v = ((const float4*)src)[i];
      tile[r][c + i * 4 + 0] = v.x;
      tile[r][c + i * 4 + 1] = v.y;
      tile[r][c + i * 4 + 2] = v.z;
      tile[r][c + i * 4 + 3] = v.w;
    }
    __syncthreads();
    union { bf16 hh[16]; uint4 u[2]; } pk;
#pragma unroll
    for (int i = 0; i < 16; ++i) pk.hh[i] = (bf16)tile[c + i][r];
    uint4* dst = (uint4*)(Wt + (size_t)(n0 + r) * K + k0 + c);
    dst[0] = pk.u[0];
    dst[1] = pk.u[1];
  } else if (blk == 768) {
    for (int i = t; i < 1536; i += 256)
      bqkv[i] = i < 512 ? bq[i] : (i < 1024 ? bk[i - 512] : bv[i - 1024]);
  } else {
    const int local = blk - 769;  // 0..1023, each handles 1024 float4s
#pragma unroll
    for (int k = 0; k < 4; ++k) {
      const int i = local * 1024 + k * 256 + t;
      float4 v = ((const float4*)x)[i];
      bf16 tv[4] = {(bf16)v.x, (bf16)v.y, (bf16)v.z, (bf16)v.w};
      ((uint2*)xb)[i] = *(const uint2*)tv;
    }
  }
}

// =====================================================================
extern "C" void kernel_launch(void* const* d_in, const int* in_sizes, int n_in,
                              void* d_out, int out_size, void* d_ws, size_t ws_size,
                              hipStream_t stream) {
  const float* x   = (const float*)d_in[0];
  const float* Wq  = (const float*)d_in[1];
  const float* bq  = (const float*)d_in[2];
  const float* Wk  = (const float*)d_in[3];
  const float* bk  = (const float*)d_in[4];
  const float* Wv  = (const float*)d_in[5];
  const float* bvp = (const float*)d_in[6];
  const float* Wo  = (const float*)d_in[7];
  const float* bo  = (const float*)d_in[8];
  const float* W1  = (const float*)d_in[9];
  const float* b1  = (const float*)d_in[10];
  const float* W2  = (const float*)d_in[11];
  const float* b2  = (const float*)d_in[12];
  const float* g1  = (const float*)d_in[13];
  const float* be1 = (const float*)d_in[14];
  const float* g2  = (const float*)d_in[15];
  const float* be2 = (const float*)d_in[16];

  char* ws = (char*)d_ws;
  size_t off = 0;
  auto alloc = [&](size_t bytes) -> void* {
    void* p = ws + off;
    off += (bytes + 255) & ~(size_t)255;
    return p;
  };
  bf16*  WqkvT = (bf16*)alloc((size_t)1536 * 512 * 2);
  float* bqkv  = (float*)alloc(1536 * 4);
  bf16*  WoT   = (bf16*)alloc((size_t)512 * 512 * 2);
  bf16*  W1T   = (bf16*)alloc((size_t)2048 * 512 * 2);
  bf16*  W2T   = (bf16*)alloc((size_t)512 * 2048 * 2);
  bf16*  xb    = (bf16*)alloc((size_t)ROWSz * 512 * 2);
  bf16*  qkv   = (bf16*)alloc((size_t)ROWSz * 1536 * 2);    // 24 MB (Q,K rows)
  bf16*  Vt    = (bf16*)alloc((size_t)32 * 64 * 2048 * 2);  // 8 MB, written by QKV epilogue
  bf16*  ctx   = (bf16*)alloc((size_t)ROWSz * 512 * 2);
  bf16*  y1    = (bf16*)alloc((size_t)ROWSz * 512 * 2);     // Wo+resid out (bf16)
  bf16*  x1b   = (bf16*)alloc((size_t)ROWSz * 512 * 2);     // LN1 out
  bf16*  hbuf  = qkv;  // 32 MB alias over qkv+Vt (dead after attention+Wo)
  bf16*  y2    = y1;   // dead after LN1

  // fused prep (weights, bias concat, x cast)
  prep_all<<<dim3(1793), 256, 0, stream>>>(Wq, Wk, Wv, Wo, W1, W2, bq, bk, bvp, x,
                                           WqkvT, WoT, W1T, W2T, bqkv, xb);

  // QKV projection (fused N=1536; Q cols pre-scaled by C2; V cols -> Vt transposed)
  gemm_bt<128, 32, 3><<<dim3(12, 64), 256, 0, stream>>>(xb, WqkvT, bqkv, nullptr, nullptr, Vt, qkv, ROWSz, 1536, 512);
  // attention (512 blocks x 8 waves; 32q/wave, t-split A:0-15 B:16-31)
  flash_attn<<<dim3(512), 512, 0, stream>>>(qkv, Vt, ctx);
  // Wo + bias + residual(xb bf16) -> y1 bf16   [split-K, 16 waves/CU]
  gemm_bt_sk<<<dim3(4, 128), 512, 0, stream>>>(ctx, WoT, bo, xb, y1, ROWSz, 512, 512);
  layer_norm_k<0><<<dim3(2048), 256, 0, stream>>>(y1, g1, be1, x1b);
  // FFN
  gemm_bt<128, 32, 2><<<dim3(16, 64), 256, 0, stream>>>(x1b, W1T, b1, nullptr, nullptr, nullptr, hbuf, ROWSz, 2048, 512);
  // FFN2 + bias + residual(x1b) -> y2 bf16     [split-K, 16 waves/CU]
  gemm_bt_sk<<<dim3(4, 128), 512, 0, stream>>>(hbuf, W2T, b2, x1b, y2, ROWSz, 512, 2048);
  layer_norm_k<1><<<dim3(2048), 256, 0, stream>>>(y2, g2, be2, d_out);
}

// Round 10
// 249.648 us; speedup vs baseline: 1.0321x; 1.0321x over previous
//
#include <hip/hip_runtime.h>
#include <hip/hip_bf16.h>
#include <stdint.h>

typedef __bf16 bf16;
typedef __attribute__((ext_vector_type(8))) __bf16 bf16x8;
typedef __attribute__((ext_vector_type(4))) float f32x4;

#define DEVI __device__ __forceinline__

constexpr int Bz = 4, Sz = 2048, Dz = 512, Hz = 8, DKz = 64, DFFz = 2048;
constexpr int ROWSz = Bz * Sz;  // 8192
constexpr float EPSf = 1e-5f;
constexpr float C2f = 0.125f * 1.44269504088896f;  // 1/sqrt(DK) * log2(e)

// ---- async global->LDS, 16B per lane. LDS dest is wave-uniform base + lane*16.
DEVI void load_lds16(void* lds, const void* g) {
  __builtin_amdgcn_global_load_lds(
      (const __attribute__((address_space(1))) void*)(uintptr_t)(g),
      (__attribute__((address_space(3))) void*)(uint32_t)(uintptr_t)(lds),
      16, 0, 0);
}

// gfx950 cross-lane half-swaps (pure VALU; all lanes active in this kernel).
DEVI void permswap32(unsigned& x, unsigned& y) {
  asm("v_permlane32_swap_b32 %0, %1" : "+v"(x), "+v"(y));
}
DEVI void permswap16(unsigned& x, unsigned& y) {
  asm("v_permlane16_swap_b32 %0, %1" : "+v"(x), "+v"(y));
}

// =====================================================================
// GEMM (best measured mix):  C = A[M,K] @ Bt[N,K]^T  +bias.
// EPI 1: bf16 = acc+bias+f32resid      2: bf16 = relu(acc+bias)
// EPI 3: QKV: col<512 Q*C2 row-major; col<1024 K row-major;
//        col>=1024 V -> aux = Vt[(b*8+h)*64+dk][s] transposed.
//        R10: V blocks (n0>=1024) do a per-wave LDS transpose and store
//        coalesced 128B runs (was: 64x 8B scatters per wave-store).
//        Safe: K-loop's last iter ends with __syncthreads -> sA/sB
//        dead; each wave uses only its OWN 8KB region (lgkmcnt only).
// EPI 4: bf16 = acc+bias+bf16resid
// =====================================================================
template <int BM, int BK, int EPI>
__global__ __launch_bounds__(256, BM == 128 ? 4 : 3) void gemm_bt(
    const bf16* __restrict__ A, const bf16* __restrict__ Bt,
    const float* __restrict__ bias, const float* __restrict__ resid,
    const bf16* __restrict__ residb, bf16* __restrict__ aux,
    void* __restrict__ Cout, int M, int N, int K) {
  constexpr int BN = 128;
  constexpr int MI = BM / 32;          // m-frags per wave
  constexpr int RPI = 512 / BK;        // rows per 16B-issue (16 @BK32, 8 @BK64)
  constexpr int AISS = (BM / 4) / RPI; // A issues per wave
  constexpr int BISS = 32 / RPI;       // B issues per wave
  __shared__ alignas(16) bf16 sA[2][BM * BK];
  __shared__ alignas(16) bf16 sB[2][BN * BK];
  const int tid = threadIdx.x;
  const int lane = tid & 63;
  const int wv = tid >> 6;
  const int n0 = blockIdx.x * BN;
  const int m0 = blockIdx.y * BM;

  const int srow = (BK == 32) ? (lane >> 2) : (lane >> 3);
  const int sch = (BK == 32) ? (((lane & 3) ^ (srow & 3)) * 8)
                             : (((lane & 7) ^ (srow & 7)) * 8);
  const bf16* gA = A + (size_t)(m0 + wv * (BM / 4) + srow) * K + sch;
  const bf16* gB = Bt + (size_t)(n0 + wv * 32 + srow) * K + sch;

  const int wm = (wv >> 1) * (BM / 2);
  const int wn = (wv & 1) * 64;
  const int fr = lane & 15;
  const int fq = lane >> 4;

  auto stage = [&](int buf, int k0) {
#pragma unroll
    for (int j = 0; j < AISS; ++j)
      load_lds16(sA[buf] + (wv * (BM / 4) + j * RPI) * BK, gA + (size_t)(j * RPI) * K + k0);
#pragma unroll
    for (int j = 0; j < BISS; ++j)
      load_lds16(sB[buf] + (wv * 32 + j * RPI) * BK, gB + (size_t)(j * RPI) * K + k0);
  };

  f32x4 acc[MI][4] = {};

  stage(0, 0);
  __syncthreads();  // barrier's vmcnt(0) drain completes tile 0

  const int niter = K / BK;
  for (int it = 0; it < niter; ++it) {
    const int cur = it & 1;
    if (it + 1 < niter) stage(cur ^ 1, (it + 1) * BK);
#pragma unroll
    for (int kk = 0; kk < BK / 32; ++kk) {
      const int fc = (BK == 32) ? ((fq ^ (fr & 3)) * 8)
                                : (((4 * kk + fq) ^ (fr & 7)) * 8);
      bf16x8 af[MI], bfr[4];
#pragma unroll
      for (int i = 0; i < MI; ++i)
        af[i] = *(const bf16x8*)(sA[cur] + (wm + i * 16 + fr) * BK + fc);
#pragma unroll
      for (int j = 0; j < 4; ++j)
        bfr[j] = *(const bf16x8*)(sB[cur] + (wn + j * 16 + fr) * BK + fc);
#pragma unroll
      for (int i = 0; i < MI; ++i)
#pragma unroll
        for (int j = 0; j < 4; ++j)
          acc[i][j] = __builtin_amdgcn_mfma_f32_16x16x32_bf16(af[i], bfr[j], acc[i][j], 0, 0, 0);
    }
    __syncthreads();  // readers done with cur + prefetch DMA drained
  }

  if (EPI == 3 && n0 >= 1024) {
    // ---- V epilogue: per-wave LDS transpose -> coalesced Vt stores.
    // Wave's 64x64 sub-tile: rows m0+wm..+63, dk = j*16+fr (head fixed).
    bf16* Tw = (wv < 2 ? (bf16*)sA : (bf16*)sB) + (wv & 1) * 4096;  // 8KB own
#pragma unroll
    for (int i = 0; i < MI; ++i) {
#pragma unroll
      for (int j = 0; j < 4; ++j) {
        const int col = n0 + wn + j * 16 + fr;
        const float bv = bias[col];
        bf16 pv[4];
#pragma unroll
        for (int r = 0; r < 4; ++r) pv[r] = (bf16)(acc[i][j][r] + bv);
        const int dk = j * 16 + fr;
        // T[dk][sloc], row 128B; XOR-swizzle chunk bits by dk&7 (=fr&7)
        const int boff = dk * 128 + ((i * 32 + fq * 8) ^ ((fr & 7) << 4));
        *(uint2*)((char*)Tw + boff) = *(const uint2*)pv;
      }
    }
    asm volatile("s_waitcnt lgkmcnt(0)" ::: "memory");  // own writes visible
    const int hh = (n0 + wn - 1024) >> 6;
    const int rowbase = m0 + wm;
    const int bb = rowbase >> 11, s0b = rowbase & 2047;
#pragma unroll
    for (int p = 0; p < 8; ++p) {
      const int dk = p * 8 + (lane >> 3);
      const int o = lane & 7;
      const uint4 v = *(const uint4*)((const char*)Tw + dk * 128 + ((o ^ (dk & 7)) << 4));
      *(uint4*)(aux + (size_t)((bb * 8 + hh) * 64 + dk) * 2048 + s0b + o * 8) = v;
    }
  } else {
#pragma unroll
    for (int i = 0; i < MI; ++i) {
#pragma unroll
      for (int j = 0; j < 4; ++j) {
        const int col = n0 + wn + j * 16 + fr;
        const float bv = bias[col];
#pragma unroll
        for (int r = 0; r < 4; ++r) {
          const int row = m0 + wm + i * 16 + fq * 4 + r;
          const size_t idx = (size_t)row * N + col;
          float v = acc[i][j][r] + bv;
          if (EPI == 1) {
            ((bf16*)Cout)[idx] = (bf16)(v + resid[idx]);
          } else if (EPI == 2) {
            ((bf16*)Cout)[idx] = (bf16)(v > 0.f ? v : 0.f);
          } else if (EPI == 3) {
            ((bf16*)Cout)[idx] = (bf16)(col < 512 ? v * C2f : v);
          } else {
            ((bf16*)Cout)[idx] = (bf16)(v + (float)residb[idx]);
          }
        }
      }
    }
  }
}

// =====================================================================
// Flash attention v8 (R8, frozen best: 50.0us): t-split + 32 q/wave.
// 8-wave blocks: waves 0-3 tiles 0-15, waves 4-7 tiles 16-31, same
// 128 q-rows; partials merged via LDS (max-free softmax => pure sums).
// Grid 512, 16 waves/CU = 4/SIMD. MfmaUtil 26% = exactly algorithmic
// MFMA content; further gains need full HK 4-cluster co-design.
// =====================================================================
__global__ __launch_bounds__(512, 4) void flash_attn(
    const bf16* __restrict__ qkv, const bf16* __restrict__ Vt,
    bf16* __restrict__ ctx) {
  const int bid = blockIdx.x;
  const int qt = bid >> 5;         // 0..15, 128-row q tiles
  const int bh = bid & 31;         // bid%8 == h -> XCD pinning per head
  const int h = bh & 7;
  const int b = bh >> 3;
  const int q0 = qt * 128;
  const int tid = threadIdx.x, lane = tid & 63, wv = tid >> 6;  // wv 0..7
  const int g = wv >> 2;           // t-group: 0 -> tiles 0..15, 1 -> 16..31
  const int wg = wv & 3;           // wave in group; owns q rows wg*32..+31
  const int fr = lane & 15, fq = lane >> 4;
  const int xsw = fr & 7;

  __shared__ alignas(16) union SMem {
    struct { bf16 K[2][2][64 * 64]; bf16 V[2][2][64 * 64]; } kv;
    float mrg[4 * 64 * 35];  // 4 waves x 64 lanes x (32 acc + 2 l + pad)
  } sm;

  const int srow = lane >> 3;                // 0..7 within 8-row issue
  const int scol = ((lane & 7) ^ srow) * 8;  // swizzled chunk (elements)

  const bf16* gK = qkv + (size_t)(b * Sz + wg * 16 + srow) * 1536 + 512 + h * 64 + scol;
  const bf16* gV = Vt + (size_t)((b * 8 + h) * 64 + wg * 16 + srow) * Sz + scol;

  auto stage = [&](int p, int t) {
    const size_t t0 = (size_t)t * 64;
    load_lds16(sm.kv.K[g][p] + (wg * 16 + 0) * 64, gK + t0 * 1536);
    load_lds16(sm.kv.K[g][p] + (wg * 16 + 8) * 64, gK + (t0 + 8) * 1536);
    load_lds16(sm.kv.V[g][p] + (wg * 16 + 0) * 64, gV + t0);
    load_lds16(sm.kv.V[g][p] + (wg * 16 + 8) * 64, gV + (size_t)8 * Sz + t0);
  };

  stage(0, g * 16);  // tile 0 of own range

  const bf16* gQf = qkv + (size_t)(b * Sz + q0 + wg * 32 + fr) * 1536 + h * 64;
  bf16x8 qb[2][2];
  qb[0][0] = *(const bf16x8*)(gQf + fq * 8);
  qb[0][1] = *(const bf16x8*)(gQf + (fq + 4) * 8);
  qb[1][0] = *(const bf16x8*)(gQf + (size_t)16 * 1536 + fq * 8);
  qb[1][1] = *(const bf16x8*)(gQf + (size_t)16 * 1536 + (fq + 4) * 8);

  asm volatile("s_waitcnt vmcnt(0)" ::: "memory");  // qb + stage(0) landed
  __builtin_amdgcn_s_barrier();
  asm volatile("" ::: "memory");

  const int colc0 = (fq ^ xsw) * 8;
  const int colc1 = ((fq + 4) ^ xsw) * 8;
  int qsrc[4];
#pragma unroll
  for (int r = 0; r < 4; ++r) qsrc[r] = (fq * 4 + r) | (lane & 48);

  const f32x4 ZERO = {0.f, 0.f, 0.f, 0.f};
  float l_part[2] = {0.f, 0.f};
  f32x4 acc_o[2][4] = {};

  for (int st = 0; st < 16; ++st) {
    const int p = st & 1;
    if (st + 1 < 16) stage(p ^ 1, g * 16 + st + 1);

    const bf16* kb = sm.kv.K[g][p];
    const bf16* vb = sm.kv.V[g][p];

    bf16x8 kf[2][4];
#pragma unroll
    for (int j = 0; j < 4; ++j) {
      kf[0][j] = *(const bf16x8*)(kb + (j * 16 + fr) * 64 + colc0);
      kf[1][j] = *(const bf16x8*)(kb + (j * 16 + fr) * 64 + colc1);
    }
    f32x4 sc[2][4];
    __builtin_amdgcn_s_setprio(1);
#pragma unroll
    for (int s = 0; s < 2; ++s)
#pragma unroll
      for (int j = 0; j < 4; ++j) {
        f32x4 z = __builtin_amdgcn_mfma_f32_16x16x32_bf16(kf[0][j], qb[s][0], ZERO, 0, 0, 0);
        sc[s][j] = __builtin_amdgcn_mfma_f32_16x16x32_bf16(kf[1][j], qb[s][1], z, 0, 0, 0);
      }
    __builtin_amdgcn_s_setprio(0);

    bf16x8 pa[2][2];
#pragma unroll
    for (int s = 0; s < 2; ++s) {
      unsigned c0[4], c1[4];
      float rs = 0.f;
#pragma unroll
      for (int j = 0; j < 4; ++j) {
        float e0 = __builtin_amdgcn_exp2f(sc[s][j][0]);
        float e1 = __builtin_amdgcn_exp2f(sc[s][j][1]);
        float e2 = __builtin_amdgcn_exp2f(sc[s][j][2]);
        float e3 = __builtin_amdgcn_exp2f(sc[s][j][3]);
        rs += (e0 + e1) + (e2 + e3);
        union { bf16 hh[2]; unsigned u; } pka, pkb;
        pka.hh[0] = (bf16)e0; pka.hh[1] = (bf16)e1;  // v_cvt_pk_bf16_f32
        pkb.hh[0] = (bf16)e2; pkb.hh[1] = (bf16)e3;
        c0[j] = pka.u;
        c1[j] = pkb.u;
      }
      l_part[s] += rs;
#pragma unroll
      for (int kk = 0; kk < 2; ++kk) {
        unsigned x0 = c0[2 * kk], y0 = c0[2 * kk + 1];
        permswap32(x0, y0);
        permswap16(x0, y0);
        unsigned x1 = c1[2 * kk], y1 = c1[2 * kk + 1];
        permswap32(x1, y1);
        permswap16(x1, y1);
        union { unsigned u[4]; bf16x8 v; } pk;
        pk.u[0] = x0; pk.u[1] = x1; pk.u[2] = y0; pk.u[3] = y1;
        pa[s][kk] = pk.v;
      }
    }

    bf16x8 vf[2][4];
#pragma unroll
    for (int j = 0; j < 4; ++j) {
      vf[0][j] = *(const bf16x8*)(vb + (j * 16 + fr) * 64 + colc0);
      vf[1][j] = *(const bf16x8*)(vb + (j * 16 + fr) * 64 + colc1);
    }
    __builtin_amdgcn_s_setprio(1);
#pragma unroll
    for (int s = 0; s < 2; ++s)
#pragma unroll
      for (int kk = 0; kk < 2; ++kk)
#pragma unroll
        for (int j = 0; j < 4; ++j)
          acc_o[s][j] = __builtin_amdgcn_mfma_f32_16x16x32_bf16(pa[s][kk], vf[kk][j], acc_o[s][j], 0, 0, 0);
    __builtin_amdgcn_s_setprio(0);

    if (st + 1 < 16) {
      asm volatile("s_waitcnt vmcnt(0)" ::: "memory");  // own stage landed
      __builtin_amdgcn_s_barrier();
      asm volatile("" ::: "memory");
    }
  }

  // ---- t-split merge: A's partials -> LDS (aliases K/V, dead now); B adds.
  __syncthreads();  // all waves done computing before mrg overwrites K/V
  if (g == 0) {
    float* mp = sm.mrg + (wg * 64 + lane) * 35;
#pragma unroll
    for (int s = 0; s < 2; ++s)
#pragma unroll
      for (int j = 0; j < 4; ++j)
#pragma unroll
        for (int r = 0; r < 4; ++r) mp[s * 16 + j * 4 + r] = acc_o[s][j][r];
    mp[32] = l_part[0];
    mp[33] = l_part[1];
  }
  __syncthreads();
  if (g == 1) {
    const float* mp = sm.mrg + (wg * 64 + lane) * 35;
#pragma unroll
    for (int s = 0; s < 2; ++s)
#pragma unroll
      for (int j = 0; j < 4; ++j)
#pragma unroll
        for (int r = 0; r < 4; ++r) acc_o[s][j][r] += mp[s * 16 + j * 4 + r];
    l_part[0] += mp[32];
    l_part[1] += mp[33];

#pragma unroll
    for (int s = 0; s < 2; ++s) {
      float l = l_part[s];
      l += __shfl_xor(l, 16, 64);
      l += __shfl_xor(l, 32, 64);
      float rl[4];
#pragma unroll
      for (int r = 0; r < 4; ++r) rl[r] = 1.0f / __shfl(l, qsrc[r], 64);
#pragma unroll
      for (int j = 0; j < 4; ++j)
#pragma unroll
        for (int r = 0; r < 4; ++r) {
          const int row = b * Sz + q0 + wg * 32 + s * 16 + fq * 4 + r;
          const int col = h * 64 + j * 16 + fr;
          ctx[(size_t)row * Dz + col] = (bf16)(acc_o[s][j][r] * rl[r]);
        }
    }
  }
}

// =====================================================================
// LayerNorm: one wave per row of 512. bf16 input; fp32 or bf16 output.
// =====================================================================
template <int OUT_F32>
__global__ __launch_bounds__(256) void layer_norm_k(
    const bf16* __restrict__ y, const float* __restrict__ g,
    const float* __restrict__ be, void* __restrict__ out) {
  const int row = blockIdx.x * 4 + (threadIdx.x >> 6);
  const int lane = threadIdx.x & 63;
  const int col = lane * 8;
  bf16x8 hv = *(const bf16x8*)(y + (size_t)row * Dz + col);
  float v[8];
  float s = 0.f, ss = 0.f;
#pragma unroll
  for (int i = 0; i < 8; ++i) {
    v[i] = (float)hv[i];
    s += v[i];
    ss += v[i] * v[i];
  }
#pragma unroll
  for (int o = 1; o < 64; o <<= 1) {
    s += __shfl_xor(s, o, 64);
    ss += __shfl_xor(ss, o, 64);
  }
  const float mu = s * (1.0f / Dz);
  const float rstd = rsqrtf(ss * (1.0f / Dz) - mu * mu + EPSf);
  const float4* g4 = (const float4*)(g + col);
  const float4* b4 = (const float4*)(be + col);
  float4 ga = g4[0], gb = g4[1], ba = b4[0], bb = b4[1];
  float o8[8];
  o8[0] = (v[0] - mu) * rstd * ga.x + ba.x;
  o8[1] = (v[1] - mu) * rstd * ga.y + ba.y;
  o8[2] = (v[2] - mu) * rstd * ga.z + ba.z;
  o8[3] = (v[3] - mu) * rstd * ga.w + ba.w;
  o8[4] = (v[4] - mu) * rstd * gb.x + bb.x;
  o8[5] = (v[5] - mu) * rstd * gb.y + bb.y;
  o8[6] = (v[6] - mu) * rstd * gb.z + bb.z;
  o8[7] = (v[7] - mu) * rstd * gb.w + bb.w;
  if (OUT_F32) {
    float4* of = (float4*)((float*)out + (size_t)row * Dz + col);
    of[0] = make_float4(o8[0], o8[1], o8[2], o8[3]);
    of[1] = make_float4(o8[4], o8[5], o8[6], o8[7]);
  } else {
    bf16 ob[8];
#pragma unroll
    for (int i = 0; i < 8; ++i) ob[i] = (bf16)o8[i];
    *(uint4*)((bf16*)out + (size_t)row * Dz + col) = *(const uint4*)ob;
  }
}

// =====================================================================
// Fused prep: all 6 weight transposes (fp32[K,N] -> bf16[N,K], 64x64
// tiles), bias concat, x -> bf16 cast. One launch.
// =====================================================================
__global__ __launch_bounds__(256) void prep_all(
    const float* __restrict__ Wq, const float* __restrict__ Wk,
    const float* __restrict__ Wv, const float* __restrict__ Wo,
    const float* __restrict__ W1, const float* __restrict__ W2,
    const float* __restrict__ bq, const float* __restrict__ bk,
    const float* __restrict__ bv, const float* __restrict__ x,
    bf16* __restrict__ WqkvT, bf16* __restrict__ WoT,
    bf16* __restrict__ W1T, bf16* __restrict__ W2T,
    float* __restrict__ bqkv, bf16* __restrict__ xb) {
  __shared__ float tile[64][65];
  const int blk = blockIdx.x;
  const int t = threadIdx.x;
  if (blk < 768) {
    const float* W;
    bf16* Wt;
    int K, N, local;
    if (blk < 64)       { W = Wq; Wt = WqkvT;                       K = 512;  N = 512;  local = blk; }
    else if (blk < 128) { W = Wk; Wt = WqkvT + (size_t)512 * 512;   K = 512;  N = 512;  local = blk - 64; }
    else if (blk < 192) { W = Wv; Wt = WqkvT + (size_t)1024 * 512;  K = 512;  N = 512;  local = blk - 128; }
    else if (blk < 256) { W = Wo; Wt = WoT;                         K = 512;  N = 512;  local = blk - 192; }
    else if (blk < 512) { W = W1; Wt = W1T;                         K = 512;  N = 2048; local = blk - 256; }
    else                { W = W2; Wt = W2T;                         K = 2048; N = 512;  local = blk - 512; }
    const int kt = K / 64;
    const int k0 = (local % kt) * 64, n0 = (local / kt) * 64;
    const int r = t >> 2, c = (t & 3) * 16;
    const float* src = W + (size_t)(k0 + r) * N + n0 + c;
#pragma unroll
    for (int i = 0; i < 4; ++i) {
      float4 v = ((const float4*)src)[i];
      tile[r][c + i * 4 + 0] = v.x;
      tile[r][c + i * 4 + 1] = v.y;
      tile[r][c + i * 4 + 2] = v.z;
      tile[r][c + i * 4 + 3] = v.w;
    }
    __syncthreads();
    union { bf16 hh[16]; uint4 u[2]; } pk;
#pragma unroll
    for (int i = 0; i < 16; ++i) pk.hh[i] = (bf16)tile[c + i][r];
    uint4* dst = (uint4*)(Wt + (size_t)(n0 + r) * K + k0 + c);
    dst[0] = pk.u[0];
    dst[1] = pk.u[1];
  } else if (blk == 768) {
    for (int i = t; i < 1536; i += 256)
      bqkv[i] = i < 512 ? bq[i] : (i < 1024 ? bk[i - 512] : bv[i - 1024]);
  } else {
    const int local = blk - 769;  // 0..1023, each handles 1024 float4s
#pragma unroll
    for (int k = 0; k < 4; ++k) {
      const int i = local * 1024 + k * 256 + t;
      float4 v = ((const float4*)x)[i];
      bf16 tv[4] = {(bf16)v.x, (bf16)v.y, (bf16)v.z, (bf16)v.w};
      ((uint2*)xb)[i] = *(const uint2*)tv;
    }
  }
}

// =====================================================================
extern "C" void kernel_launch(void* const* d_in, const int* in_sizes, int n_in,
                              void* d_out, int out_size, void* d_ws, size_t ws_size,
                              hipStream_t stream) {
  const float* x   = (const float*)d_in[0];
  const float* Wq  = (const float*)d_in[1];
  const float* bq  = (const float*)d_in[2];
  const float* Wk  = (const float*)d_in[3];
  const float* bk  = (const float*)d_in[4];
  const float* Wv  = (const float*)d_in[5];
  const float* bvp = (const float*)d_in[6];
  const float* Wo  = (const float*)d_in[7];
  const float* bo  = (const float*)d_in[8];
  const float* W1  = (const float*)d_in[9];
  const float* b1  = (const float*)d_in[10];
  const float* W2  = (const float*)d_in[11];
  const float* b2  = (const float*)d_in[12];
  const float* g1  = (const float*)d_in[13];
  const float* be1 = (const float*)d_in[14];
  const float* g2  = (const float*)d_in[15];
  const float* be2 = (const float*)d_in[16];

  char* ws = (char*)d_ws;
  size_t off = 0;
  auto alloc = [&](size_t bytes) -> void* {
    void* p = ws + off;
    off += (bytes + 255) & ~(size_t)255;
    return p;
  };
  bf16*  WqkvT = (bf16*)alloc((size_t)1536 * 512 * 2);
  float* bqkv  = (float*)alloc(1536 * 4);
  bf16*  WoT   = (bf16*)alloc((size_t)512 * 512 * 2);
  bf16*  W1T   = (bf16*)alloc((size_t)2048 * 512 * 2);
  bf16*  W2T   = (bf16*)alloc((size_t)512 * 2048 * 2);
  bf16*  xb    = (bf16*)alloc((size_t)ROWSz * 512 * 2);
  bf16*  qkv   = (bf16*)alloc((size_t)ROWSz * 1536 * 2);    // 24 MB (Q,K rows)
  bf16*  Vt    = (bf16*)alloc((size_t)32 * 64 * 2048 * 2);  // 8 MB, written by QKV epilogue
  bf16*  ctx   = (bf16*)alloc((size_t)ROWSz * 512 * 2);
  bf16*  y1    = (bf16*)alloc((size_t)ROWSz * 512 * 2);     // Wo+resid out (bf16)
  bf16*  x1b   = (bf16*)alloc((size_t)ROWSz * 512 * 2);     // LN1 out
  bf16*  hbuf  = qkv;  // 32 MB alias over qkv+Vt (dead after attention+Wo)
  bf16*  y2    = y1;   // dead after LN1

  // fused prep (weights, bias concat, x cast)
  prep_all<<<dim3(1793), 256, 0, stream>>>(Wq, Wk, Wv, Wo, W1, W2, bq, bk, bvp, x,
                                           WqkvT, WoT, W1T, W2T, bqkv, xb);

  // QKV projection (fused N=1536; Q cols pre-scaled by C2; V cols -> Vt transposed)
  gemm_bt<128, 32, 3><<<dim3(12, 64), 256, 0, stream>>>(xb, WqkvT, bqkv, nullptr, nullptr, Vt, qkv, ROWSz, 1536, 512);
  // attention (512 blocks x 8 waves; 32q/wave, t-split A:0-15 B:16-31)
  flash_attn<<<dim3(512), 512, 0, stream>>>(qkv, Vt, ctx);
  // Wo + bias + residual(xb bf16) -> y1 bf16
  gemm_bt<64, 64, 4><<<dim3(4, 128), 256, 0, stream>>>(ctx, WoT, bo, nullptr, xb, nullptr, y1, ROWSz, 512, 512);
  layer_norm_k<0><<<dim3(2048), 256, 0, stream>>>(y1, g1, be1, x1b);
  // FFN
  gemm_bt<128, 32, 2><<<dim3(16, 64), 256, 0, stream>>>(x1b, W1T, b1, nullptr, nullptr, nullptr, hbuf, ROWSz, 2048, 512);
  gemm_bt<64, 64, 4><<<dim3(4, 128), 256, 0, stream>>>(hbuf, W2T, b2, nullptr, x1b, nullptr, y2, ROWSz, 512, 2048);
  layer_norm_k<1><<<dim3(2048), 256, 0, stream>>>(y2, g2, be2, d_out);
}

// Round 12
// 246.060 us; speedup vs baseline: 1.0472x; 1.0146x over previous
//
#include <hip/hip_runtime.h>
#include <hip/hip_bf16.h>
#include <stdint.h>

typedef __bf16 bf16;
typedef __attribute__((ext_vector_type(8))) __bf16 bf16x8;
typedef __attribute__((ext_vector_type(4))) float f32x4;

#define DEVI __device__ __forceinline__

constexpr int Bz = 4, Sz = 2048, Dz = 512, Hz = 8, DKz = 64, DFFz = 2048;
constexpr int ROWSz = Bz * Sz;  // 8192
constexpr float EPSf = 1e-5f;
constexpr float C2f = 0.125f * 1.44269504088896f;  // 1/sqrt(DK) * log2(e)

// ---- async global->LDS, 16B per lane. LDS dest is wave-uniform base + lane*16.
DEVI void load_lds16(void* lds, const void* g) {
  __builtin_amdgcn_global_load_lds(
      (const __attribute__((address_space(1))) void*)(uintptr_t)(g),
      (__attribute__((address_space(3))) void*)(uint32_t)(uintptr_t)(lds),
      16, 0, 0);
}

// gfx950 cross-lane half-swaps (pure VALU; all lanes active in this kernel).
DEVI void permswap32(unsigned& x, unsigned& y) {
  asm("v_permlane32_swap_b32 %0, %1" : "+v"(x), "+v"(y));
}
DEVI void permswap16(unsigned& x, unsigned& y) {
  asm("v_permlane16_swap_b32 %0, %1" : "+v"(x), "+v"(y));
}

// =====================================================================
// GEMM (best measured mix):  C = A[M,K] @ Bt[N,K]^T  +bias.
// EPI 1: bf16 = acc+bias+f32resid      2: bf16 = relu(acc+bias)
// EPI 3: QKV: col<512 Q*C2 row-major; col<1024 K row-major;
//        col>=1024 V -> aux = Vt[(b*8+h)*64+dk][s] transposed (LDS
//        transpose epilogue, coalesced 128B runs).
// EPI 4: bf16 = acc+bias+bf16resid
// =====================================================================
template <int BM, int BK, int EPI>
__global__ __launch_bounds__(256, BM == 128 ? 4 : 3) void gemm_bt(
    const bf16* __restrict__ A, const bf16* __restrict__ Bt,
    const float* __restrict__ bias, const float* __restrict__ resid,
    const bf16* __restrict__ residb, bf16* __restrict__ aux,
    void* __restrict__ Cout, int M, int N, int K) {
  constexpr int BN = 128;
  constexpr int MI = BM / 32;          // m-frags per wave
  constexpr int RPI = 512 / BK;        // rows per 16B-issue (16 @BK32, 8 @BK64)
  constexpr int AISS = (BM / 4) / RPI; // A issues per wave
  constexpr int BISS = 32 / RPI;       // B issues per wave
  __shared__ alignas(16) bf16 sA[2][BM * BK];
  __shared__ alignas(16) bf16 sB[2][BN * BK];
  const int tid = threadIdx.x;
  const int lane = tid & 63;
  const int wv = tid >> 6;
  const int n0 = blockIdx.x * BN;
  const int m0 = blockIdx.y * BM;

  const int srow = (BK == 32) ? (lane >> 2) : (lane >> 3);
  const int sch = (BK == 32) ? (((lane & 3) ^ (srow & 3)) * 8)
                             : (((lane & 7) ^ (srow & 7)) * 8);
  const bf16* gA = A + (size_t)(m0 + wv * (BM / 4) + srow) * K + sch;
  const bf16* gB = Bt + (size_t)(n0 + wv * 32 + srow) * K + sch;

  const int wm = (wv >> 1) * (BM / 2);
  const int wn = (wv & 1) * 64;
  const int fr = lane & 15;
  const int fq = lane >> 4;

  auto stage = [&](int buf, int k0) {
#pragma unroll
    for (int j = 0; j < AISS; ++j)
      load_lds16(sA[buf] + (wv * (BM / 4) + j * RPI) * BK, gA + (size_t)(j * RPI) * K + k0);
#pragma unroll
    for (int j = 0; j < BISS; ++j)
      load_lds16(sB[buf] + (wv * 32 + j * RPI) * BK, gB + (size_t)(j * RPI) * K + k0);
  };

  f32x4 acc[MI][4] = {};

  stage(0, 0);
  __syncthreads();  // barrier's vmcnt(0) drain completes tile 0

  const int niter = K / BK;
  for (int it = 0; it < niter; ++it) {
    const int cur = it & 1;
    if (it + 1 < niter) stage(cur ^ 1, (it + 1) * BK);
#pragma unroll
    for (int kk = 0; kk < BK / 32; ++kk) {
      const int fc = (BK == 32) ? ((fq ^ (fr & 3)) * 8)
                                : (((4 * kk + fq) ^ (fr & 7)) * 8);
      bf16x8 af[MI], bfr[4];
#pragma unroll
      for (int i = 0; i < MI; ++i)
        af[i] = *(const bf16x8*)(sA[cur] + (wm + i * 16 + fr) * BK + fc);
#pragma unroll
      for (int j = 0; j < 4; ++j)
        bfr[j] = *(const bf16x8*)(sB[cur] + (wn + j * 16 + fr) * BK + fc);
#pragma unroll
      for (int i = 0; i < MI; ++i)
#pragma unroll
        for (int j = 0; j < 4; ++j)
          acc[i][j] = __builtin_amdgcn_mfma_f32_16x16x32_bf16(af[i], bfr[j], acc[i][j], 0, 0, 0);
    }
    __syncthreads();  // readers done with cur + prefetch DMA drained
  }

  if (EPI == 3 && n0 >= 1024) {
    // ---- V epilogue: per-wave LDS transpose -> coalesced Vt stores.
    bf16* Tw = (wv < 2 ? (bf16*)sA : (bf16*)sB) + (wv & 1) * 4096;  // 8KB own
#pragma unroll
    for (int i = 0; i < MI; ++i) {
#pragma unroll
      for (int j = 0; j < 4; ++j) {
        const int col = n0 + wn + j * 16 + fr;
        const float bv = bias[col];
        bf16 pv[4];
#pragma unroll
        for (int r = 0; r < 4; ++r) pv[r] = (bf16)(acc[i][j][r] + bv);
        const int dk = j * 16 + fr;
        const int boff = dk * 128 + ((i * 32 + fq * 8) ^ ((fr & 7) << 4));
        *(uint2*)((char*)Tw + boff) = *(const uint2*)pv;
      }
    }
    asm volatile("s_waitcnt lgkmcnt(0)" ::: "memory");  // own writes visible
    const int hh = (n0 + wn - 1024) >> 6;
    const int rowbase = m0 + wm;
    const int bb = rowbase >> 11, s0b = rowbase & 2047;
#pragma unroll
    for (int p = 0; p < 8; ++p) {
      const int dk = p * 8 + (lane >> 3);
      const int o = lane & 7;
      const uint4 v = *(const uint4*)((const char*)Tw + dk * 128 + ((o ^ (dk & 7)) << 4));
      *(uint4*)(aux + (size_t)((bb * 8 + hh) * 64 + dk) * 2048 + s0b + o * 8) = v;
    }
  } else {
#pragma unroll
    for (int i = 0; i < MI; ++i) {
#pragma unroll
      for (int j = 0; j < 4; ++j) {
        const int col = n0 + wn + j * 16 + fr;
        const float bv = bias[col];
#pragma unroll
        for (int r = 0; r < 4; ++r) {
          const int row = m0 + wm + i * 16 + fq * 4 + r;
          const size_t idx = (size_t)row * N + col;
          float v = acc[i][j][r] + bv;
          if (EPI == 1) {
            ((bf16*)Cout)[idx] = (bf16)(v + resid[idx]);
          } else if (EPI == 2) {
            ((bf16*)Cout)[idx] = (bf16)(v > 0.f ? v : 0.f);
          } else if (EPI == 3) {
            ((bf16*)Cout)[idx] = (bf16)(col < 512 ? v * C2f : v);
          } else {
            ((bf16*)Cout)[idx] = (bf16)(v + (float)residb[idx]);
          }
        }
      }
    }
  }
}

// =====================================================================
// 256x256 deep-pipelined GEMM (R11/R12 resubmit, FFN1):
// C = relu(A @ Bt^T + bias). GEMM fleet ~180us at ~290 TF is the
// dominant mass; 128²/2-buffer barrier-drain is its measured ceiling
// (m131-m140 null) while 256²+counted-vmcnt+phase-split is the proven
// regime (m201). FFN1 grid maps perfectly: 8x32 = 256 blocks = 1/CU.
// BK=32, THREE K-tile dbufs (96KB) -> provable ledger:
//   - buffer staged at tile t ((cur+2)%3) was last read at tile t-1,
//     behind that tile's end barrier (no mid-tile overwrites);
//   - tile t's reads guarded by vmcnt(4)+barrier at end of t-1
//     (retires t's 4 loads, keeps t+1's in flight; NEVER 0 mid-loop);
//   - 2 phases/tile x 16 MFMA, stage A(t+2) ph0 / B(t+2) ph1.
// Fragment/swizzle/C-write math byte-inherited from gemm_bt BK=32.
// Per-wave output 128x64 (8 m-frags x 4 n-frags), acc = 128 VGPR.
// =====================================================================
__global__ __launch_bounds__(512, 2) void gemm_256(
    const bf16* __restrict__ A, const bf16* __restrict__ Bt,
    const float* __restrict__ bias, bf16* __restrict__ Cout,
    int M, int N, int K) {
  constexpr int BM = 256, BN = 256, BK = 32;
  __shared__ alignas(16) bf16 sA[3][BM * BK];  // 16KB each
  __shared__ alignas(16) bf16 sB[3][BN * BK];
  const int tid = threadIdx.x, lane = tid & 63, wv = tid >> 6;  // wv 0..7
  const int wr = wv >> 2, wc = wv & 3;  // wave -> 128x64 output sub-tile
  const int n0 = blockIdx.x * BN, m0 = blockIdx.y * BM;
  const int fr = lane & 15, fq = lane >> 4;

  // staging: issue covers 128 rows (8 waves x 16); 2 issues per tensor-tile
  const int srow = lane >> 2;                      // 0..15
  const int sch = ((lane & 3) ^ (srow & 3)) * 8;   // pre-swizzled chunk
  const bf16* gA = A + (size_t)(m0 + wv * 16 + srow) * K + sch;
  const bf16* gB = Bt + (size_t)(n0 + wv * 16 + srow) * K + sch;

  auto stageA = [&](int buf, int k0) {
    load_lds16(sA[buf] + (wv * 16) * BK, gA + k0);
    load_lds16(sA[buf] + (128 + wv * 16) * BK, gA + (size_t)128 * K + k0);
  };
  auto stageB = [&](int buf, int k0) {
    load_lds16(sB[buf] + (wv * 16) * BK, gB + k0);
    load_lds16(sB[buf] + (128 + wv * 16) * BK, gB + (size_t)128 * K + k0);
  };

  const int fc = (fq ^ (fr & 3)) * 8;  // read-side swizzle (row&3 == fr&3)

  f32x4 acc[8][4] = {};

  // prologue: tiles 0,1 staged; tile 0's 4 loads retired (tile 1's stay out)
  stageA(0, 0);
  stageB(0, 0);
  stageA(1, BK);
  stageB(1, BK);
  asm volatile("s_waitcnt vmcnt(4)" ::: "memory");
  __builtin_amdgcn_s_barrier();
  asm volatile("" ::: "memory");

  const int niter = K / BK;  // 16 for FFN1
  int cur = 0;
  for (int t = 0; t < niter; ++t) {
    const bf16* a = sA[cur];
    const bf16* b = sB[cur];
    int nb = cur + 2;
    if (nb >= 3) nb -= 3;
    const bool pf = (t + 2 < niter);

    // ---- phase 0: B-frags (all 4, reused in phase 1) + A-frags 0-3
    bf16x8 bfr[4], af[4];
#pragma unroll
    for (int j = 0; j < 4; ++j)
      bfr[j] = *(const bf16x8*)(b + (wc * 64 + j * 16 + fr) * BK + fc);
#pragma unroll
    for (int i = 0; i < 4; ++i)
      af[i] = *(const bf16x8*)(a + (wr * 128 + i * 16 + fr) * BK + fc);
    if (pf) stageA(nb, (t + 2) * BK);
    __builtin_amdgcn_s_setprio(1);
#pragma unroll
    for (int i = 0; i < 4; ++i)
#pragma unroll
      for (int j = 0; j < 4; ++j)
        acc[i][j] = __builtin_amdgcn_mfma_f32_16x16x32_bf16(af[i], bfr[j], acc[i][j], 0, 0, 0);
    __builtin_amdgcn_s_setprio(0);
    __builtin_amdgcn_s_barrier();  // phase alignment
    asm volatile("" ::: "memory");

    // ---- phase 1: A-frags 4-7; stage B(t+2); tile-end counted sync
    bf16x8 af2[4];
#pragma unroll
    for (int i = 0; i < 4; ++i)
      af2[i] = *(const bf16x8*)(a + (wr * 128 + (4 + i) * 16 + fr) * BK + fc);
    if (pf) stageB(nb, (t + 2) * BK);
    __builtin_amdgcn_s_setprio(1);
#pragma unroll
    for (int i = 0; i < 4; ++i)
#pragma unroll
      for (int j = 0; j < 4; ++j)
        acc[4 + i][j] = __builtin_amdgcn_mfma_f32_16x16x32_bf16(af2[i], bfr[j], acc[4 + i][j], 0, 0, 0);
    __builtin_amdgcn_s_setprio(0);
    if (t + 1 < niter) {
      if (pf) asm volatile("s_waitcnt vmcnt(4)" ::: "memory");  // t+1 ready
      else    asm volatile("s_waitcnt vmcnt(0)" ::: "memory");  // drain tail
      __builtin_amdgcn_s_barrier();
      asm volatile("" ::: "memory");
    }
    cur = cur == 2 ? 0 : cur + 1;
  }

  // ---- epilogue: relu(acc + bias) -> bf16 (same mapping as gemm_bt)
#pragma unroll
  for (int i = 0; i < 8; ++i)
#pragma unroll
    for (int j = 0; j < 4; ++j) {
      const int col = n0 + wc * 64 + j * 16 + fr;
      const float bv = bias[col];
#pragma unroll
      for (int r = 0; r < 4; ++r) {
        const int row = m0 + wr * 128 + i * 16 + fq * 4 + r;
        float v = acc[i][j][r] + bv;
        Cout[(size_t)row * N + col] = (bf16)(v > 0.f ? v : 0.f);
      }
    }
}

// =====================================================================
// Flash attention v8 (R8, frozen best: 50.0us): t-split + 32 q/wave.
// 8-wave blocks: waves 0-3 tiles 0-15, waves 4-7 tiles 16-31, same
// 128 q-rows; partials merged via LDS (max-free softmax => pure sums).
// Grid 512, 16 waves/CU = 4/SIMD. MfmaUtil 26% = exactly algorithmic
// MFMA content; further gains need full HK 4-cluster co-design.
// =====================================================================
__global__ __launch_bounds__(512, 4) void flash_attn(
    const bf16* __restrict__ qkv, const bf16* __restrict__ Vt,
    bf16* __restrict__ ctx) {
  const int bid = blockIdx.x;
  const int qt = bid >> 5;         // 0..15, 128-row q tiles
  const int bh = bid & 31;         // bid%8 == h -> XCD pinning per head
  const int h = bh & 7;
  const int b = bh >> 3;
  const int q0 = qt * 128;
  const int tid = threadIdx.x, lane = tid & 63, wv = tid >> 6;  // wv 0..7
  const int g = wv >> 2;           // t-group: 0 -> tiles 0..15, 1 -> 16..31
  const int wg = wv & 3;           // wave in group; owns q rows wg*32..+31
  const int fr = lane & 15, fq = lane >> 4;
  const int xsw = fr & 7;

  __shared__ alignas(16) union SMem {
    struct { bf16 K[2][2][64 * 64]; bf16 V[2][2][64 * 64]; } kv;
    float mrg[4 * 64 * 35];  // 4 waves x 64 lanes x (32 acc + 2 l + pad)
  } sm;

  const int srow = lane >> 3;                // 0..7 within 8-row issue
  const int scol = ((lane & 7) ^ srow) * 8;  // swizzled chunk (elements)

  const bf16* gK = qkv + (size_t)(b * Sz + wg * 16 + srow) * 1536 + 512 + h * 64 + scol;
  const bf16* gV = Vt + (size_t)((b * 8 + h) * 64 + wg * 16 + srow) * Sz + scol;

  auto stage = [&](int p, int t) {
    const size_t t0 = (size_t)t * 64;
    load_lds16(sm.kv.K[g][p] + (wg * 16 + 0) * 64, gK + t0 * 1536);
    load_lds16(sm.kv.K[g][p] + (wg * 16 + 8) * 64, gK + (t0 + 8) * 1536);
    load_lds16(sm.kv.V[g][p] + (wg * 16 + 0) * 64, gV + t0);
    load_lds16(sm.kv.V[g][p] + (wg * 16 + 8) * 64, gV + (size_t)8 * Sz + t0);
  };

  stage(0, g * 16);  // tile 0 of own range

  const bf16* gQf = qkv + (size_t)(b * Sz + q0 + wg * 32 + fr) * 1536 + h * 64;
  bf16x8 qb[2][2];
  qb[0][0] = *(const bf16x8*)(gQf + fq * 8);
  qb[0][1] = *(const bf16x8*)(gQf + (fq + 4) * 8);
  qb[1][0] = *(const bf16x8*)(gQf + (size_t)16 * 1536 + fq * 8);
  qb[1][1] = *(const bf16x8*)(gQf + (size_t)16 * 1536 + (fq + 4) * 8);

  asm volatile("s_waitcnt vmcnt(0)" ::: "memory");  // qb + stage(0) landed
  __builtin_amdgcn_s_barrier();
  asm volatile("" ::: "memory");

  const int colc0 = (fq ^ xsw) * 8;
  const int colc1 = ((fq + 4) ^ xsw) * 8;
  int qsrc[4];
#pragma unroll
  for (int r = 0; r < 4; ++r) qsrc[r] = (fq * 4 + r) | (lane & 48);

  const f32x4 ZERO = {0.f, 0.f, 0.f, 0.f};
  float l_part[2] = {0.f, 0.f};
  f32x4 acc_o[2][4] = {};

  for (int st = 0; st < 16; ++st) {
    const int p = st & 1;
    if (st + 1 < 16) stage(p ^ 1, g * 16 + st + 1);

    const bf16* kb = sm.kv.K[g][p];
    const bf16* vb = sm.kv.V[g][p];

    bf16x8 kf[2][4];
#pragma unroll
    for (int j = 0; j < 4; ++j) {
      kf[0][j] = *(const bf16x8*)(kb + (j * 16 + fr) * 64 + colc0);
      kf[1][j] = *(const bf16x8*)(kb + (j * 16 + fr) * 64 + colc1);
    }
    f32x4 sc[2][4];
    __builtin_amdgcn_s_setprio(1);
#pragma unroll
    for (int s = 0; s < 2; ++s)
#pragma unroll
      for (int j = 0; j < 4; ++j) {
        f32x4 z = __builtin_amdgcn_mfma_f32_16x16x32_bf16(kf[0][j], qb[s][0], ZERO, 0, 0, 0);
        sc[s][j] = __builtin_amdgcn_mfma_f32_16x16x32_bf16(kf[1][j], qb[s][1], z, 0, 0, 0);
      }
    __builtin_amdgcn_s_setprio(0);

    bf16x8 pa[2][2];
#pragma unroll
    for (int s = 0; s < 2; ++s) {
      unsigned c0[4], c1[4];
      float rs = 0.f;
#pragma unroll
      for (int j = 0; j < 4; ++j) {
        float e0 = __builtin_amdgcn_exp2f(sc[s][j][0]);
        float e1 = __builtin_amdgcn_exp2f(sc[s][j][1]);
        float e2 = __builtin_amdgcn_exp2f(sc[s][j][2]);
        float e3 = __builtin_amdgcn_exp2f(sc[s][j][3]);
        rs += (e0 + e1) + (e2 + e3);
        union { bf16 hh[2]; unsigned u; } pka, pkb;
        pka.hh[0] = (bf16)e0; pka.hh[1] = (bf16)e1;  // v_cvt_pk_bf16_f32
        pkb.hh[0] = (bf16)e2; pkb.hh[1] = (bf16)e3;
        c0[j] = pka.u;
        c1[j] = pkb.u;
      }
      l_part[s] += rs;
#pragma unroll
      for (int kk = 0; kk < 2; ++kk) {
        unsigned x0 = c0[2 * kk], y0 = c0[2 * kk + 1];
        permswap32(x0, y0);
        permswap16(x0, y0);
        unsigned x1 = c1[2 * kk], y1 = c1[2 * kk + 1];
        permswap32(x1, y1);
        permswap16(x1, y1);
        union { unsigned u[4]; bf16x8 v; } pk;
        pk.u[0] = x0; pk.u[1] = x1; pk.u[2] = y0; pk.u[3] = y1;
        pa[s][kk] = pk.v;
      }
    }

    bf16x8 vf[2][4];
#pragma unroll
    for (int j = 0; j < 4; ++j) {
      vf[0][j] = *(const bf16x8*)(vb + (j * 16 + fr) * 64 + colc0);
      vf[1][j] = *(const bf16x8*)(vb + (j * 16 + fr) * 64 + colc1);
    }
    __builtin_amdgcn_s_setprio(1);
#pragma unroll
    for (int s = 0; s < 2; ++s)
#pragma unroll
      for (int kk = 0; kk < 2; ++kk)
#pragma unroll
        for (int j = 0; j < 4; ++j)
          acc_o[s][j] = __builtin_amdgcn_mfma_f32_16x16x32_bf16(pa[s][kk], vf[kk][j], acc_o[s][j], 0, 0, 0);
    __builtin_amdgcn_s_setprio(0);

    if (st + 1 < 16) {
      asm volatile("s_waitcnt vmcnt(0)" ::: "memory");  // own stage landed
      __builtin_amdgcn_s_barrier();
      asm volatile("" ::: "memory");
    }
  }

  // ---- t-split merge: A's partials -> LDS (aliases K/V, dead now); B adds.
  __syncthreads();  // all waves done computing before mrg overwrites K/V
  if (g == 0) {
    float* mp = sm.mrg + (wg * 64 + lane) * 35;
#pragma unroll
    for (int s = 0; s < 2; ++s)
#pragma unroll
      for (int j = 0; j < 4; ++j)
#pragma unroll
        for (int r = 0; r < 4; ++r) mp[s * 16 + j * 4 + r] = acc_o[s][j][r];
    mp[32] = l_part[0];
    mp[33] = l_part[1];
  }
  __syncthreads();
  if (g == 1) {
    const float* mp = sm.mrg + (wg * 64 + lane) * 35;
#pragma unroll
    for (int s = 0; s < 2; ++s)
#pragma unroll
      for (int j = 0; j < 4; ++j)
#pragma unroll
        for (int r = 0; r < 4; ++r) acc_o[s][j][r] += mp[s * 16 + j * 4 + r];
    l_part[0] += mp[32];
    l_part[1] += mp[33];

#pragma unroll
    for (int s = 0; s < 2; ++s) {
      float l = l_part[s];
      l += __shfl_xor(l, 16, 64);
      l += __shfl_xor(l, 32, 64);
      float rl[4];
#pragma unroll
      for (int r = 0; r < 4; ++r) rl[r] = 1.0f / __shfl(l, qsrc[r], 64);
#pragma unroll
      for (int j = 0; j < 4; ++j)
#pragma unroll
        for (int r = 0; r < 4; ++r) {
          const int row = b * Sz + q0 + wg * 32 + s * 16 + fq * 4 + r;
          const int col = h * 64 + j * 16 + fr;
          ctx[(size_t)row * Dz + col] = (bf16)(acc_o[s][j][r] * rl[r]);
        }
    }
  }
}

// =====================================================================
// LayerNorm: one wave per row of 512. bf16 input; fp32 or bf16 output.
// =====================================================================
template <int OUT_F32>
__global__ __launch_bounds__(256) void layer_norm_k(
    const bf16* __restrict__ y, const float* __restrict__ g,
    const float* __restrict__ be, void* __restrict__ out) {
  const int row = blockIdx.x * 4 + (threadIdx.x >> 6);
  const int lane = threadIdx.x & 63;
  const int col = lane * 8;
  bf16x8 hv = *(const bf16x8*)(y + (size_t)row * Dz + col);
  float v[8];
  float s = 0.f, ss = 0.f;
#pragma unroll
  for (int i = 0; i < 8; ++i) {
    v[i] = (float)hv[i];
    s += v[i];
    ss += v[i] * v[i];
  }
#pragma unroll
  for (int o = 1; o < 64; o <<= 1) {
    s += __shfl_xor(s, o, 64);
    ss += __shfl_xor(ss, o, 64);
  }
  const float mu = s * (1.0f / Dz);
  const float rstd = rsqrtf(ss * (1.0f / Dz) - mu * mu + EPSf);
  const float4* g4 = (const float4*)(g + col);
  const float4* b4 = (const float4*)(be + col);
  float4 ga = g4[0], gb = g4[1], ba = b4[0], bb = b4[1];
  float o8[8];
  o8[0] = (v[0] - mu) * rstd * ga.x + ba.x;
  o8[1] = (v[1] - mu) * rstd * ga.y + ba.y;
  o8[2] = (v[2] - mu) * rstd * ga.z + ba.z;
  o8[3] = (v[3] - mu) * rstd * ga.w + ba.w;
  o8[4] = (v[4] - mu) * rstd * gb.x + bb.x;
  o8[5] = (v[5] - mu) * rstd * gb.y + bb.y;
  o8[6] = (v[6] - mu) * rstd * gb.z + bb.z;
  o8[7] = (v[7] - mu) * rstd * gb.w + bb.w;
  if (OUT_F32) {
    float4* of = (float4*)((float*)out + (size_t)row * Dz + col);
    of[0] = make_float4(o8[0], o8[1], o8[2], o8[3]);
    of[1] = make_float4(o8[4], o8[5], o8[6], o8[7]);
  } else {
    bf16 ob[8];
#pragma unroll
    for (int i = 0; i < 8; ++i) ob[i] = (bf16)o8[i];
    *(uint4*)((bf16*)out + (size_t)row * Dz + col) = *(const uint4*)ob;
  }
}

// =====================================================================
// Fused prep: all 6 weight transposes (fp32[K,N] -> bf16[N,K], 64x64
// tiles), bias concat, x -> bf16 cast. One launch.
// =====================================================================
__global__ __launch_bounds__(256) void prep_all(
    const float* __restrict__ Wq, const float* __restrict__ Wk,
    const float* __restrict__ Wv, const float* __restrict__ Wo,
    const float* __restrict__ W1, const float* __restrict__ W2,
    const float* __restrict__ bq, const float* __restrict__ bk,
    const float* __restrict__ bv, const float* __restrict__ x,
    bf16* __restrict__ WqkvT, bf16* __restrict__ WoT,
    bf16* __restrict__ W1T, bf16* __restrict__ W2T,
    float* __restrict__ bqkv, bf16* __restrict__ xb) {
  __shared__ float tile[64][65];
  const int blk = blockIdx.x;
  const int t = threadIdx.x;
  if (blk < 768) {
    const float* W;
    bf16* Wt;
    int K, N, local;
    if (blk < 64)       { W = Wq; Wt = WqkvT;                       K = 512;  N = 512;  local = blk; }
    else if (blk < 128) { W = Wk; Wt = WqkvT + (size_t)512 * 512;   K = 512;  N = 512;  local = blk - 64; }
    else if (blk < 192) { W = Wv; Wt = WqkvT + (size_t)1024 * 512;  K = 512;  N = 512;  local = blk - 128; }
    else if (blk < 256) { W = Wo; Wt = WoT;                         K = 512;  N = 512;  local = blk - 192; }
    else if (blk < 512) { W = W1; Wt = W1T;                         K = 512;  N = 2048; local = blk - 256; }
    else                { W = W2; Wt = W2T;                         K = 2048; N = 512;  local = blk - 512; }
    const int kt = K / 64;
    const int k0 = (local % kt) * 64, n0 = (local / kt) * 64;
    const int r = t >> 2, c = (t & 3) * 16;
    const float* src = W + (size_t)(k0 + r) * N + n0 + c;
#pragma unroll
    for (int i = 0; i < 4; ++i) {
      float4 v = ((const float4*)src)[i];
      tile[r][c + i * 4 + 0] = v.x;
      tile[r][c + i * 4 + 1] = v.y;
      tile[r][c + i * 4 + 2] = v.z;
      tile[r][c + i * 4 + 3] = v.w;
    }
    __syncthreads();
    union { bf16 hh[16]; uint4 u[2]; } pk;
#pragma unroll
    for (int i = 0; i < 16; ++i) pk.hh[i] = (bf16)tile[c + i][r];
    uint4* dst = (uint4*)(Wt + (size_t)(n0 + r) * K + k0 + c);
    dst[0] = pk.u[0];
    dst[1] = pk.u[1];
  } else if (blk == 768) {
    for (int i = t; i < 1536; i += 256)
      bqkv[i] = i < 512 ? bq[i] : (i < 1024 ? bk[i - 512] : bv[i - 1024]);
  } else {
    const int local = blk - 769;  // 0..1023, each handles 1024 float4s
#pragma unroll
    for (int k = 0; k < 4; ++k) {
      const int i = local * 1024 + k * 256 + t;
      float4 v = ((const float4*)x)[i];
      bf16 tv[4] = {(bf16)v.x, (bf16)v.y, (bf16)v.z, (bf16)v.w};
      ((uint2*)xb)[i] = *(const uint2*)tv;
    }
  }
}

// =====================================================================
extern "C" void kernel_launch(void* const* d_in, const int* in_sizes, int n_in,
                              void* d_out, int out_size, void* d_ws, size_t ws_size,
                              hipStream_t stream) {
  const float* x   = (const float*)d_in[0];
  const float* Wq  = (const float*)d_in[1];
  const float* bq  = (const float*)d_in[2];
  const float* Wk  = (const float*)d_in[3];
  const float* bk  = (const float*)d_in[4];
  const float* Wv  = (const float*)d_in[5];
  const float* bvp = (const float*)d_in[6];
  const float* Wo  = (const float*)d_in[7];
  const float* bo  = (const float*)d_in[8];
  const float* W1  = (const float*)d_in[9];
  const float* b1  = (const float*)d_in[10];
  const float* W2  = (const float*)d_in[11];
  const float* b2  = (const float*)d_in[12];
  const float* g1  = (const float*)d_in[13];
  const float* be1 = (const float*)d_in[14];
  const float* g2  = (const float*)d_in[15];
  const float* be2 = (const float*)d_in[16];

  char* ws = (char*)d_ws;
  size_t off = 0;
  auto alloc = [&](size_t bytes) -> void* {
    void* p = ws + off;
    off += (bytes + 255) & ~(size_t)255;
    return p;
  };
  bf16*  WqkvT = (bf16*)alloc((size_t)1536 * 512 * 2);
  float* bqkv  = (float*)alloc(1536 * 4);
  bf16*  WoT   = (bf16*)alloc((size_t)512 * 512 * 2);
  bf16*  W1T   = (bf16*)alloc((size_t)2048 * 512 * 2);
  bf16*  W2T   = (bf16*)alloc((size_t)512 * 2048 * 2);
  bf16*  xb    = (bf16*)alloc((size_t)ROWSz * 512 * 2);
  bf16*  qkv   = (bf16*)alloc((size_t)ROWSz * 1536 * 2);    // 24 MB (Q,K rows)
  bf16*  Vt    = (bf16*)alloc((size_t)32 * 64 * 2048 * 2);  // 8 MB, written by QKV epilogue
  bf16*  ctx   = (bf16*)alloc((size_t)ROWSz * 512 * 2);
  bf16*  y1    = (bf16*)alloc((size_t)ROWSz * 512 * 2);     // Wo+resid out (bf16)
  bf16*  x1b   = (bf16*)alloc((size_t)ROWSz * 512 * 2);     // LN1 out
  bf16*  hbuf  = qkv;  // 32 MB alias over qkv+Vt (dead after attention+Wo)
  bf16*  y2    = y1;   // dead after LN1

  // fused prep (weights, bias concat, x cast)
  prep_all<<<dim3(1793), 256, 0, stream>>>(Wq, Wk, Wv, Wo, W1, W2, bq, bk, bvp, x,
                                           WqkvT, WoT, W1T, W2T, bqkv, xb);

  // QKV projection (fused N=1536; Q cols pre-scaled by C2; V cols -> Vt transposed)
  gemm_bt<128, 32, 3><<<dim3(12, 64), 256, 0, stream>>>(xb, WqkvT, bqkv, nullptr, nullptr, Vt, qkv, ROWSz, 1536, 512);
  // attention (512 blocks x 8 waves; 32q/wave, t-split A:0-15 B:16-31)
  flash_attn<<<dim3(512), 512, 0, stream>>>(qkv, Vt, ctx);
  // Wo + bias + residual(xb bf16) -> y1 bf16
  gemm_bt<64, 64, 4><<<dim3(4, 128), 256, 0, stream>>>(ctx, WoT, bo, nullptr, xb, nullptr, y1, ROWSz, 512, 512);
  layer_norm_k<0><<<dim3(2048), 256, 0, stream>>>(y1, g1, be1, x1b);
  // FFN1: 256x256 deep-pipelined tile (256 blocks = 1/CU, counted vmcnt)
  gemm_256<<<dim3(8, 32), 512, 0, stream>>>(x1b, W1T, b1, hbuf, ROWSz, 2048, 512);
  gemm_bt<64, 64, 4><<<dim3(4, 128), 256, 0, stream>>>(hbuf, W2T, b2, nullptr, x1b, nullptr, y2, ROWSz, 512, 2048);
  layer_norm_k<1><<<dim3(2048), 256, 0, stream>>>(y2, g2, be2, d_out);
}

// Round 13
// 236.768 us; speedup vs baseline: 1.0883x; 1.0392x over previous
//
#include <hip/hip_runtime.h>
#include <hip/hip_bf16.h>
#include <stdint.h>

typedef __bf16 bf16;
typedef __attribute__((ext_vector_type(8))) __bf16 bf16x8;
typedef __attribute__((ext_vector_type(4))) float f32x4;

#define DEVI __device__ __forceinline__

constexpr int Bz = 4, Sz = 2048, Dz = 512, Hz = 8, DKz = 64, DFFz = 2048;
constexpr int ROWSz = Bz * Sz;  // 8192
constexpr float EPSf = 1e-5f;
constexpr float C2f = 0.125f * 1.44269504088896f;  // 1/sqrt(DK) * log2(e)

// ---- async global->LDS, 16B per lane. LDS dest is wave-uniform base + lane*16.
DEVI void load_lds16(void* lds, const void* g) {
  __builtin_amdgcn_global_load_lds(
      (const __attribute__((address_space(1))) void*)(uintptr_t)(g),
      (__attribute__((address_space(3))) void*)(uint32_t)(uintptr_t)(lds),
      16, 0, 0);
}

// gfx950 cross-lane half-swaps (pure VALU; all lanes active in this kernel).
DEVI void permswap32(unsigned& x, unsigned& y) {
  asm("v_permlane32_swap_b32 %0, %1" : "+v"(x), "+v"(y));
}
DEVI void permswap16(unsigned& x, unsigned& y) {
  asm("v_permlane16_swap_b32 %0, %1" : "+v"(x), "+v"(y));
}

// T1 XCD-aware block remap (R13). HW round-robins linear block id over
// 8 XCDs (xcd = lid%8). Remap so each XCD owns a CONTIGUOUS sid range
// sweeping bx fastest: blocks sharing an A row-panel (same by) land on
// one XCD -> A-panel + weight panel become XCD-L2-resident. Bijective
// when nblocks%8==0 (all our GEMM grids: 768/512/256/512).
DEVI void xcd_remap(int& bx, int& by) {
  const int gx = gridDim.x;
  const int nb = gx * gridDim.y;
  const int lid = blockIdx.y * gx + blockIdx.x;
  const int per = nb >> 3;  // nb % 8 == 0 at every call site
  const int sid = (lid & 7) * per + (lid >> 3);
  bx = sid % gx;
  by = sid / gx;
}

// =====================================================================
// GEMM (best measured mix):  C = A[M,K] @ Bt[N,K]^T  +bias.
// EPI 1: bf16 = acc+bias+f32resid      2: bf16 = relu(acc+bias)
// EPI 3: QKV: col<512 Q*C2 row-major; col<1024 K row-major;
//        col>=1024 V -> aux = Vt[(b*8+h)*64+dk][s] transposed (LDS
//        transpose epilogue, coalesced 128B runs).
// EPI 4: bf16 = acc+bias+bf16resid
// =====================================================================
template <int BM, int BK, int EPI>
__global__ __launch_bounds__(256, BM == 128 ? 4 : 3) void gemm_bt(
    const bf16* __restrict__ A, const bf16* __restrict__ Bt,
    const float* __restrict__ bias, const float* __restrict__ resid,
    const bf16* __restrict__ residb, bf16* __restrict__ aux,
    void* __restrict__ Cout, int M, int N, int K) {
  constexpr int BN = 128;
  constexpr int MI = BM / 32;          // m-frags per wave
  constexpr int RPI = 512 / BK;        // rows per 16B-issue (16 @BK32, 8 @BK64)
  constexpr int AISS = (BM / 4) / RPI; // A issues per wave
  constexpr int BISS = 32 / RPI;       // B issues per wave
  __shared__ alignas(16) bf16 sA[2][BM * BK];
  __shared__ alignas(16) bf16 sB[2][BN * BK];
  const int tid = threadIdx.x;
  const int lane = tid & 63;
  const int wv = tid >> 6;
  int bx, by;
  xcd_remap(bx, by);
  const int n0 = bx * BN;
  const int m0 = by * BM;

  const int srow = (BK == 32) ? (lane >> 2) : (lane >> 3);
  const int sch = (BK == 32) ? (((lane & 3) ^ (srow & 3)) * 8)
                             : (((lane & 7) ^ (srow & 7)) * 8);
  const bf16* gA = A + (size_t)(m0 + wv * (BM / 4) + srow) * K + sch;
  const bf16* gB = Bt + (size_t)(n0 + wv * 32 + srow) * K + sch;

  const int wm = (wv >> 1) * (BM / 2);
  const int wn = (wv & 1) * 64;
  const int fr = lane & 15;
  const int fq = lane >> 4;

  auto stage = [&](int buf, int k0) {
#pragma unroll
    for (int j = 0; j < AISS; ++j)
      load_lds16(sA[buf] + (wv * (BM / 4) + j * RPI) * BK, gA + (size_t)(j * RPI) * K + k0);
#pragma unroll
    for (int j = 0; j < BISS; ++j)
      load_lds16(sB[buf] + (wv * 32 + j * RPI) * BK, gB + (size_t)(j * RPI) * K + k0);
  };

  f32x4 acc[MI][4] = {};

  stage(0, 0);
  __syncthreads();  // barrier's vmcnt(0) drain completes tile 0

  const int niter = K / BK;
  for (int it = 0; it < niter; ++it) {
    const int cur = it & 1;
    if (it + 1 < niter) stage(cur ^ 1, (it + 1) * BK);
#pragma unroll
    for (int kk = 0; kk < BK / 32; ++kk) {
      const int fc = (BK == 32) ? ((fq ^ (fr & 3)) * 8)
                                : (((4 * kk + fq) ^ (fr & 7)) * 8);
      bf16x8 af[MI], bfr[4];
#pragma unroll
      for (int i = 0; i < MI; ++i)
        af[i] = *(const bf16x8*)(sA[cur] + (wm + i * 16 + fr) * BK + fc);
#pragma unroll
      for (int j = 0; j < 4; ++j)
        bfr[j] = *(const bf16x8*)(sB[cur] + (wn + j * 16 + fr) * BK + fc);
#pragma unroll
      for (int i = 0; i < MI; ++i)
#pragma unroll
        for (int j = 0; j < 4; ++j)
          acc[i][j] = __builtin_amdgcn_mfma_f32_16x16x32_bf16(af[i], bfr[j], acc[i][j], 0, 0, 0);
    }
    __syncthreads();  // readers done with cur + prefetch DMA drained
  }

  if (EPI == 3 && n0 >= 1024) {
    // ---- V epilogue: per-wave LDS transpose -> coalesced Vt stores.
    bf16* Tw = (wv < 2 ? (bf16*)sA : (bf16*)sB) + (wv & 1) * 4096;  // 8KB own
#pragma unroll
    for (int i = 0; i < MI; ++i) {
#pragma unroll
      for (int j = 0; j < 4; ++j) {
        const int col = n0 + wn + j * 16 + fr;
        const float bv = bias[col];
        bf16 pv[4];
#pragma unroll
        for (int r = 0; r < 4; ++r) pv[r] = (bf16)(acc[i][j][r] + bv);
        const int dk = j * 16 + fr;
        const int boff = dk * 128 + ((i * 32 + fq * 8) ^ ((fr & 7) << 4));
        *(uint2*)((char*)Tw + boff) = *(const uint2*)pv;
      }
    }
    asm volatile("s_waitcnt lgkmcnt(0)" ::: "memory");  // own writes visible
    const int hh = (n0 + wn - 1024) >> 6;
    const int rowbase = m0 + wm;
    const int bb = rowbase >> 11, s0b = rowbase & 2047;
#pragma unroll
    for (int p = 0; p < 8; ++p) {
      const int dk = p * 8 + (lane >> 3);
      const int o = lane & 7;
      const uint4 v = *(const uint4*)((const char*)Tw + dk * 128 + ((o ^ (dk & 7)) << 4));
      *(uint4*)(aux + (size_t)((bb * 8 + hh) * 64 + dk) * 2048 + s0b + o * 8) = v;
    }
  } else {
#pragma unroll
    for (int i = 0; i < MI; ++i) {
#pragma unroll
      for (int j = 0; j < 4; ++j) {
        const int col = n0 + wn + j * 16 + fr;
        const float bv = bias[col];
#pragma unroll
        for (int r = 0; r < 4; ++r) {
          const int row = m0 + wm + i * 16 + fq * 4 + r;
          const size_t idx = (size_t)row * N + col;
          float v = acc[i][j][r] + bv;
          if (EPI == 1) {
            ((bf16*)Cout)[idx] = (bf16)(v + resid[idx]);
          } else if (EPI == 2) {
            ((bf16*)Cout)[idx] = (bf16)(v > 0.f ? v : 0.f);
          } else if (EPI == 3) {
            ((bf16*)Cout)[idx] = (bf16)(col < 512 ? v * C2f : v);
          } else {
            ((bf16*)Cout)[idx] = (bf16)(v + (float)residb[idx]);
          }
        }
      }
    }
  }
}

// =====================================================================
// 256x256 deep-pipelined GEMM (R11, FFN1): C = relu(A @ Bt^T + bias).
// BK=32, THREE K-tile dbufs (96KB), counted vmcnt(4) (never 0 mid-loop),
// 2 phases/tile x 16 MFMA, stage A(t+2) ph0 / B(t+2) ph1. Ledger: buf
// staged at tile t was last read at tile t-1 behind its end barrier;
// tile t's reads guarded by end-of-(t-1) vmcnt(4)+barrier.
// R13: + XCD remap (grid 8x32=256, %8==0).
// =====================================================================
__global__ __launch_bounds__(512, 2) void gemm_256(
    const bf16* __restrict__ A, const bf16* __restrict__ Bt,
    const float* __restrict__ bias, bf16* __restrict__ Cout,
    int M, int N, int K) {
  constexpr int BM = 256, BN = 256, BK = 32;
  __shared__ alignas(16) bf16 sA[3][BM * BK];  // 16KB each
  __shared__ alignas(16) bf16 sB[3][BN * BK];
  const int tid = threadIdx.x, lane = tid & 63, wv = tid >> 6;  // wv 0..7
  const int wr = wv >> 2, wc = wv & 3;  // wave -> 128x64 output sub-tile
  int bx, by;
  xcd_remap(bx, by);
  const int n0 = bx * BN, m0 = by * BM;
  const int fr = lane & 15, fq = lane >> 4;

  // staging: issue covers 128 rows (8 waves x 16); 2 issues per tensor-tile
  const int srow = lane >> 2;                      // 0..15
  const int sch = ((lane & 3) ^ (srow & 3)) * 8;   // pre-swizzled chunk
  const bf16* gA = A + (size_t)(m0 + wv * 16 + srow) * K + sch;
  const bf16* gB = Bt + (size_t)(n0 + wv * 16 + srow) * K + sch;

  auto stageA = [&](int buf, int k0) {
    load_lds16(sA[buf] + (wv * 16) * BK, gA + k0);
    load_lds16(sA[buf] + (128 + wv * 16) * BK, gA + (size_t)128 * K + k0);
  };
  auto stageB = [&](int buf, int k0) {
    load_lds16(sB[buf] + (wv * 16) * BK, gB + k0);
    load_lds16(sB[buf] + (128 + wv * 16) * BK, gB + (size_t)128 * K + k0);
  };

  const int fc = (fq ^ (fr & 3)) * 8;  // read-side swizzle (row&3 == fr&3)

  f32x4 acc[8][4] = {};

  // prologue: tiles 0,1 staged; tile 0's 4 loads retired (tile 1's stay out)
  stageA(0, 0);
  stageB(0, 0);
  stageA(1, BK);
  stageB(1, BK);
  asm volatile("s_waitcnt vmcnt(4)" ::: "memory");
  __builtin_amdgcn_s_barrier();
  asm volatile("" ::: "memory");

  const int niter = K / BK;  // 16 for FFN1
  int cur = 0;
  for (int t = 0; t < niter; ++t) {
    const bf16* a = sA[cur];
    const bf16* b = sB[cur];
    int nb = cur + 2;
    if (nb >= 3) nb -= 3;
    const bool pf = (t + 2 < niter);

    // ---- phase 0: B-frags (all 4, reused in phase 1) + A-frags 0-3
    bf16x8 bfr[4], af[4];
#pragma unroll
    for (int j = 0; j < 4; ++j)
      bfr[j] = *(const bf16x8*)(b + (wc * 64 + j * 16 + fr) * BK + fc);
#pragma unroll
    for (int i = 0; i < 4; ++i)
      af[i] = *(const bf16x8*)(a + (wr * 128 + i * 16 + fr) * BK + fc);
    if (pf) stageA(nb, (t + 2) * BK);
    __builtin_amdgcn_s_setprio(1);
#pragma unroll
    for (int i = 0; i < 4; ++i)
#pragma unroll
      for (int j = 0; j < 4; ++j)
        acc[i][j] = __builtin_amdgcn_mfma_f32_16x16x32_bf16(af[i], bfr[j], acc[i][j], 0, 0, 0);
    __builtin_amdgcn_s_setprio(0);
    __builtin_amdgcn_s_barrier();  // phase alignment
    asm volatile("" ::: "memory");

    // ---- phase 1: A-frags 4-7; stage B(t+2); tile-end counted sync
    bf16x8 af2[4];
#pragma unroll
    for (int i = 0; i < 4; ++i)
      af2[i] = *(const bf16x8*)(a + (wr * 128 + (4 + i) * 16 + fr) * BK + fc);
    if (pf) stageB(nb, (t + 2) * BK);
    __builtin_amdgcn_s_setprio(1);
#pragma unroll
    for (int i = 0; i < 4; ++i)
#pragma unroll
      for (int j = 0; j < 4; ++j)
        acc[4 + i][j] = __builtin_amdgcn_mfma_f32_16x16x32_bf16(af2[i], bfr[j], acc[4 + i][j], 0, 0, 0);
    __builtin_amdgcn_s_setprio(0);
    if (t + 1 < niter) {
      if (pf) asm volatile("s_waitcnt vmcnt(4)" ::: "memory");  // t+1 ready
      else    asm volatile("s_waitcnt vmcnt(0)" ::: "memory");  // drain tail
      __builtin_amdgcn_s_barrier();
      asm volatile("" ::: "memory");
    }
    cur = cur == 2 ? 0 : cur + 1;
  }

  // ---- epilogue: relu(acc + bias) -> bf16 (same mapping as gemm_bt)
#pragma unroll
  for (int i = 0; i < 8; ++i)
#pragma unroll
    for (int j = 0; j < 4; ++j) {
      const int col = n0 + wc * 64 + j * 16 + fr;
      const float bv = bias[col];
#pragma unroll
      for (int r = 0; r < 4; ++r) {
        const int row = m0 + wr * 128 + i * 16 + fq * 4 + r;
        float v = acc[i][j][r] + bv;
        Cout[(size_t)row * N + col] = (bf16)(v > 0.f ? v : 0.f);
      }
    }
}

// =====================================================================
// Flash attention v8 (R8, frozen best: 50.0us): t-split + 32 q/wave.
// 8-wave blocks: waves 0-3 tiles 0-15, waves 4-7 tiles 16-31, same
// 128 q-rows; partials merged via LDS (max-free softmax => pure sums).
// Grid 512, 16 waves/CU = 4/SIMD. MfmaUtil 26% = exactly algorithmic
// MFMA content; further gains need full HK 4-cluster co-design.
// =====================================================================
__global__ __launch_bounds__(512, 4) void flash_attn(
    const bf16* __restrict__ qkv, const bf16* __restrict__ Vt,
    bf16* __restrict__ ctx) {
  const int bid = blockIdx.x;
  const int qt = bid >> 5;         // 0..15, 128-row q tiles
  const int bh = bid & 31;         // bid%8 == h -> XCD pinning per head
  const int h = bh & 7;
  const int b = bh >> 3;
  const int q0 = qt * 128;
  const int tid = threadIdx.x, lane = tid & 63, wv = tid >> 6;  // wv 0..7
  const int g = wv >> 2;           // t-group: 0 -> tiles 0..15, 1 -> 16..31
  const int wg = wv & 3;           // wave in group; owns q rows wg*32..+31
  const int fr = lane & 15, fq = lane >> 4;
  const int xsw = fr & 7;

  __shared__ alignas(16) union SMem {
    struct { bf16 K[2][2][64 * 64]; bf16 V[2][2][64 * 64]; } kv;
    float mrg[4 * 64 * 35];  // 4 waves x 64 lanes x (32 acc + 2 l + pad)
  } sm;

  const int srow = lane >> 3;                // 0..7 within 8-row issue
  const int scol = ((lane & 7) ^ srow) * 8;  // swizzled chunk (elements)

  const bf16* gK = qkv + (size_t)(b * Sz + wg * 16 + srow) * 1536 + 512 + h * 64 + scol;
  const bf16* gV = Vt + (size_t)((b * 8 + h) * 64 + wg * 16 + srow) * Sz + scol;

  auto stage = [&](int p, int t) {
    const size_t t0 = (size_t)t * 64;
    load_lds16(sm.kv.K[g][p] + (wg * 16 + 0) * 64, gK + t0 * 1536);
    load_lds16(sm.kv.K[g][p] + (wg * 16 + 8) * 64, gK + (t0 + 8) * 1536);
    load_lds16(sm.kv.V[g][p] + (wg * 16 + 0) * 64, gV + t0);
    load_lds16(sm.kv.V[g][p] + (wg * 16 + 8) * 64, gV + (size_t)8 * Sz + t0);
  };

  stage(0, g * 16);  // tile 0 of own range

  const bf16* gQf = qkv + (size_t)(b * Sz + q0 + wg * 32 + fr) * 1536 + h * 64;
  bf16x8 qb[2][2];
  qb[0][0] = *(const bf16x8*)(gQf + fq * 8);
  qb[0][1] = *(const bf16x8*)(gQf + (fq + 4) * 8);
  qb[1][0] = *(const bf16x8*)(gQf + (size_t)16 * 1536 + fq * 8);
  qb[1][1] = *(const bf16x8*)(gQf + (size_t)16 * 1536 + (fq + 4) * 8);

  asm volatile("s_waitcnt vmcnt(0)" ::: "memory");  // qb + stage(0) landed
  __builtin_amdgcn_s_barrier();
  asm volatile("" ::: "memory");

  const int colc0 = (fq ^ xsw) * 8;
  const int colc1 = ((fq + 4) ^ xsw) * 8;
  int qsrc[4];
#pragma unroll
  for (int r = 0; r < 4; ++r) qsrc[r] = (fq * 4 + r) | (lane & 48);

  const f32x4 ZERO = {0.f, 0.f, 0.f, 0.f};
  float l_part[2] = {0.f, 0.f};
  f32x4 acc_o[2][4] = {};

  for (int st = 0; st < 16; ++st) {
    const int p = st & 1;
    if (st + 1 < 16) stage(p ^ 1, g * 16 + st + 1);

    const bf16* kb = sm.kv.K[g][p];
    const bf16* vb = sm.kv.V[g][p];

    bf16x8 kf[2][4];
#pragma unroll
    for (int j = 0; j < 4; ++j) {
      kf[0][j] = *(const bf16x8*)(kb + (j * 16 + fr) * 64 + colc0);
      kf[1][j] = *(const bf16x8*)(kb + (j * 16 + fr) * 64 + colc1);
    }
    f32x4 sc[2][4];
    __builtin_amdgcn_s_setprio(1);
#pragma unroll
    for (int s = 0; s < 2; ++s)
#pragma unroll
      for (int j = 0; j < 4; ++j) {
        f32x4 z = __builtin_amdgcn_mfma_f32_16x16x32_bf16(kf[0][j], qb[s][0], ZERO, 0, 0, 0);
        sc[s][j] = __builtin_amdgcn_mfma_f32_16x16x32_bf16(kf[1][j], qb[s][1], z, 0, 0, 0);
      }
    __builtin_amdgcn_s_setprio(0);

    bf16x8 pa[2][2];
#pragma unroll
    for (int s = 0; s < 2; ++s) {
      unsigned c0[4], c1[4];
      float rs = 0.f;
#pragma unroll
      for (int j = 0; j < 4; ++j) {
        float e0 = __builtin_amdgcn_exp2f(sc[s][j][0]);
        float e1 = __builtin_amdgcn_exp2f(sc[s][j][1]);
        float e2 = __builtin_amdgcn_exp2f(sc[s][j][2]);
        float e3 = __builtin_amdgcn_exp2f(sc[s][j][3]);
        rs += (e0 + e1) + (e2 + e3);
        union { bf16 hh[2]; unsigned u; } pka, pkb;
        pka.hh[0] = (bf16)e0; pka.hh[1] = (bf16)e1;  // v_cvt_pk_bf16_f32
        pkb.hh[0] = (bf16)e2; pkb.hh[1] = (bf16)e3;
        c0[j] = pka.u;
        c1[j] = pkb.u;
      }
      l_part[s] += rs;
#pragma unroll
      for (int kk = 0; kk < 2; ++kk) {
        unsigned x0 = c0[2 * kk], y0 = c0[2 * kk + 1];
        permswap32(x0, y0);
        permswap16(x0, y0);
        unsigned x1 = c1[2 * kk], y1 = c1[2 * kk + 1];
        permswap32(x1, y1);
        permswap16(x1, y1);
        union { unsigned u[4]; bf16x8 v; } pk;
        pk.u[0] = x0; pk.u[1] = x1; pk.u[2] = y0; pk.u[3] = y1;
        pa[s][kk] = pk.v;
      }
    }

    bf16x8 vf[2][4];
#pragma unroll
    for (int j = 0; j < 4; ++j) {
      vf[0][j] = *(const bf16x8*)(vb + (j * 16 + fr) * 64 + colc0);
      vf[1][j] = *(const bf16x8*)(vb + (j * 16 + fr) * 64 + colc1);
    }
    __builtin_amdgcn_s_setprio(1);
#pragma unroll
    for (int s = 0; s < 2; ++s)
#pragma unroll
      for (int kk = 0; kk < 2; ++kk)
#pragma unroll
        for (int j = 0; j < 4; ++j)
          acc_o[s][j] = __builtin_amdgcn_mfma_f32_16x16x32_bf16(pa[s][kk], vf[kk][j], acc_o[s][j], 0, 0, 0);
    __builtin_amdgcn_s_setprio(0);

    if (st + 1 < 16) {
      asm volatile("s_waitcnt vmcnt(0)" ::: "memory");  // own stage landed
      __builtin_amdgcn_s_barrier();
      asm volatile("" ::: "memory");
    }
  }

  // ---- t-split merge: A's partials -> LDS (aliases K/V, dead now); B adds.
  __syncthreads();  // all waves done computing before mrg overwrites K/V
  if (g == 0) {
    float* mp = sm.mrg + (wg * 64 + lane) * 35;
#pragma unroll
    for (int s = 0; s < 2; ++s)
#pragma unroll
      for (int j = 0; j < 4; ++j)
#pragma unroll
        for (int r = 0; r < 4; ++r) mp[s * 16 + j * 4 + r] = acc_o[s][j][r];
    mp[32] = l_part[0];
    mp[33] = l_part[1];
  }
  __syncthreads();
  if (g == 1) {
    const float* mp = sm.mrg + (wg * 64 + lane) * 35;
#pragma unroll
    for (int s = 0; s < 2; ++s)
#pragma unroll
      for (int j = 0; j < 4; ++j)
#pragma unroll
        for (int r = 0; r < 4; ++r) acc_o[s][j][r] += mp[s * 16 + j * 4 + r];
    l_part[0] += mp[32];
    l_part[1] += mp[33];

#pragma unroll
    for (int s = 0; s < 2; ++s) {
      float l = l_part[s];
      l += __shfl_xor(l, 16, 64);
      l += __shfl_xor(l, 32, 64);
      float rl[4];
#pragma unroll
      for (int r = 0; r < 4; ++r) rl[r] = 1.0f / __shfl(l, qsrc[r], 64);
#pragma unroll
      for (int j = 0; j < 4; ++j)
#pragma unroll
        for (int r = 0; r < 4; ++r) {
          const int row = b * Sz + q0 + wg * 32 + s * 16 + fq * 4 + r;
          const int col = h * 64 + j * 16 + fr;
          ctx[(size_t)row * Dz + col] = (bf16)(acc_o[s][j][r] * rl[r]);
        }
    }
  }
}

// =====================================================================
// LayerNorm: one wave per row of 512. bf16 input; fp32 or bf16 output.
// =====================================================================
template <int OUT_F32>
__global__ __launch_bounds__(256) void layer_norm_k(
    const bf16* __restrict__ y, const float* __restrict__ g,
    const float* __restrict__ be, void* __restrict__ out) {
  const int row = blockIdx.x * 4 + (threadIdx.x >> 6);
  const int lane = threadIdx.x & 63;
  const int col = lane * 8;
  bf16x8 hv = *(const bf16x8*)(y + (size_t)row * Dz + col);
  float v[8];
  float s = 0.f, ss = 0.f;
#pragma unroll
  for (int i = 0; i < 8; ++i) {
    v[i] = (float)hv[i];
    s += v[i];
    ss += v[i] * v[i];
  }
#pragma unroll
  for (int o = 1; o < 64; o <<= 1) {
    s += __shfl_xor(s, o, 64);
    ss += __shfl_xor(ss, o, 64);
  }
  const float mu = s * (1.0f / Dz);
  const float rstd = rsqrtf(ss * (1.0f / Dz) - mu * mu + EPSf);
  const float4* g4 = (const float4*)(g + col);
  const float4* b4 = (const float4*)(be + col);
  float4 ga = g4[0], gb = g4[1], ba = b4[0], bb = b4[1];
  float o8[8];
  o8[0] = (v[0] - mu) * rstd * ga.x + ba.x;
  o8[1] = (v[1] - mu) * rstd * ga.y + ba.y;
  o8[2] = (v[2] - mu) * rstd * ga.z + ba.z;
  o8[3] = (v[3] - mu) * rstd * ga.w + ba.w;
  o8[4] = (v[4] - mu) * rstd * gb.x + bb.x;
  o8[5] = (v[5] - mu) * rstd * gb.y + bb.y;
  o8[6] = (v[6] - mu) * rstd * gb.z + bb.z;
  o8[7] = (v[7] - mu) * rstd * gb.w + bb.w;
  if (OUT_F32) {
    float4* of = (float4*)((float*)out + (size_t)row * Dz + col);
    of[0] = make_float4(o8[0], o8[1], o8[2], o8[3]);
    of[1] = make_float4(o8[4], o8[5], o8[6], o8[7]);
  } else {
    bf16 ob[8];
#pragma unroll
    for (int i = 0; i < 8; ++i) ob[i] = (bf16)o8[i];
    *(uint4*)((bf16*)out + (size_t)row * Dz + col) = *(const uint4*)ob;
  }
}

// =====================================================================
// Fused prep: all 6 weight transposes (fp32[K,N] -> bf16[N,K], 64x64
// tiles), bias concat, x -> bf16 cast. One launch.
// =====================================================================
__global__ __launch_bounds__(256) void prep_all(
    const float* __restrict__ Wq, const float* __restrict__ Wk,
    const float* __restrict__ Wv, const float* __restrict__ Wo,
    const float* __restrict__ W1, const float* __restrict__ W2,
    const float* __restrict__ bq, const float* __restrict__ bk,
    const float* __restrict__ bv, const float* __restrict__ x,
    bf16* __restrict__ WqkvT, bf16* __restrict__ WoT,
    bf16* __restrict__ W1T, bf16* __restrict__ W2T,
    float* __restrict__ bqkv, bf16* __restrict__ xb) {
  __shared__ float tile[64][65];
  const int blk = blockIdx.x;
  const int t = threadIdx.x;
  if (blk < 768) {
    const float* W;
    bf16* Wt;
    int K, N, local;
    if (blk < 64)       { W = Wq; Wt = WqkvT;                       K = 512;  N = 512;  local = blk; }
    else if (blk < 128) { W = Wk; Wt = WqkvT + (size_t)512 * 512;   K = 512;  N = 512;  local = blk - 64; }
    else if (blk < 192) { W = Wv; Wt = WqkvT + (size_t)1024 * 512;  K = 512;  N = 512;  local = blk - 128; }
    else if (blk < 256) { W = Wo; Wt = WoT;                         K = 512;  N = 512;  local = blk - 192; }
    else if (blk < 512) { W = W1; Wt = W1T;                         K = 512;  N = 2048; local = blk - 256; }
    else                { W = W2; Wt = W2T;                         K = 2048; N = 512;  local = blk - 512; }
    const int kt = K / 64;
    const int k0 = (local % kt) * 64, n0 = (local / kt) * 64;
    const int r = t >> 2, c = (t & 3) * 16;
    const float* src = W + (size_t)(k0 + r) * N + n0 + c;
#pragma unroll
    for (int i = 0; i < 4; ++i) {
      float4 v = ((const float4*)src)[i];
      tile[r][c + i * 4 + 0] = v.x;
      tile[r][c + i * 4 + 1] = v.y;
      tile[r][c + i * 4 + 2] = v.z;
      tile[r][c + i * 4 + 3] = v.w;
    }
    __syncthreads();
    union { bf16 hh[16]; uint4 u[2]; } pk;
#pragma unroll
    for (int i = 0; i < 16; ++i) pk.hh[i] = (bf16)tile[c + i][r];
    uint4* dst = (uint4*)(Wt + (size_t)(n0 + r) * K + k0 + c);
    dst[0] = pk.u[0];
    dst[1] = pk.u[1];
  } else if (blk == 768) {
    for (int i = t; i < 1536; i += 256)
      bqkv[i] = i < 512 ? bq[i] : (i < 1024 ? bk[i - 512] : bv[i - 1024]);
  } else {
    const int local = blk - 769;  // 0..1023, each handles 1024 float4s
#pragma unroll
    for (int k = 0; k < 4; ++k) {
      const int i = local * 1024 + k * 256 + t;
      float4 v = ((const float4*)x)[i];
      bf16 tv[4] = {(bf16)v.x, (bf16)v.y, (bf16)v.z, (bf16)v.w};
      ((uint2*)xb)[i] = *(const uint2*)tv;
    }
  }
}

// =====================================================================
extern "C" void kernel_launch(void* const* d_in, const int* in_sizes, int n_in,
                              void* d_out, int out_size, void* d_ws, size_t ws_size,
                              hipStream_t stream) {
  const float* x   = (const float*)d_in[0];
  const float* Wq  = (const float*)d_in[1];
  const float* bq  = (const float*)d_in[2];
  const float* Wk  = (const float*)d_in[3];
  const float* bk  = (const float*)d_in[4];
  const float* Wv  = (const float*)d_in[5];
  const float* bvp = (const float*)d_in[6];
  const float* Wo  = (const float*)d_in[7];
  const float* bo  = (const float*)d_in[8];
  const float* W1  = (const float*)d_in[9];
  const float* b1  = (const float*)d_in[10];
  const float* W2  = (const float*)d_in[11];
  const float* b2  = (const float*)d_in[12];
  const float* g1  = (const float*)d_in[13];
  const float* be1 = (const float*)d_in[14];
  const float* g2  = (const float*)d_in[15];
  const float* be2 = (const float*)d_in[16];

  char* ws = (char*)d_ws;
  size_t off = 0;
  auto alloc = [&](size_t bytes) -> void* {
    void* p = ws + off;
    off += (bytes + 255) & ~(size_t)255;
    return p;
  };
  bf16*  WqkvT = (bf16*)alloc((size_t)1536 * 512 * 2);
  float* bqkv  = (float*)alloc(1536 * 4);
  bf16*  WoT   = (bf16*)alloc((size_t)512 * 512 * 2);
  bf16*  W1T   = (bf16*)alloc((size_t)2048 * 512 * 2);
  bf16*  W2T   = (bf16*)alloc((size_t)512 * 2048 * 2);
  bf16*  xb    = (bf16*)alloc((size_t)ROWSz * 512 * 2);
  bf16*  qkv   = (bf16*)alloc((size_t)ROWSz * 1536 * 2);    // 24 MB (Q,K rows)
  bf16*  Vt    = (bf16*)alloc((size_t)32 * 64 * 2048 * 2);  // 8 MB, written by QKV epilogue
  bf16*  ctx   = (bf16*)alloc((size_t)ROWSz * 512 * 2);
  bf16*  y1    = (bf16*)alloc((size_t)ROWSz * 512 * 2);     // Wo+resid out (bf16)
  bf16*  x1b   = (bf16*)alloc((size_t)ROWSz * 512 * 2);     // LN1 out
  bf16*  hbuf  = qkv;  // 32 MB alias over qkv+Vt (dead after attention+Wo)
  bf16*  y2    = y1;   // dead after LN1

  // fused prep (weights, bias concat, x cast)
  prep_all<<<dim3(1793), 256, 0, stream>>>(Wq, Wk, Wv, Wo, W1, W2, bq, bk, bvp, x,
                                           WqkvT, WoT, W1T, W2T, bqkv, xb);

  // QKV projection (fused N=1536; Q cols pre-scaled by C2; V cols -> Vt transposed)
  gemm_bt<128, 32, 3><<<dim3(12, 64), 256, 0, stream>>>(xb, WqkvT, bqkv, nullptr, nullptr, Vt, qkv, ROWSz, 1536, 512);
  // attention (512 blocks x 8 waves; 32q/wave, t-split A:0-15 B:16-31)
  flash_attn<<<dim3(512), 512, 0, stream>>>(qkv, Vt, ctx);
  // Wo + bias + residual(xb bf16) -> y1 bf16
  gemm_bt<64, 64, 4><<<dim3(4, 128), 256, 0, stream>>>(ctx, WoT, bo, nullptr, xb, nullptr, y1, ROWSz, 512, 512);
  layer_norm_k<0><<<dim3(2048), 256, 0, stream>>>(y1, g1, be1, x1b);
  // FFN1: 256x256 deep-pipelined tile (256 blocks = 1/CU, counted vmcnt)
  gemm_256<<<dim3(8, 32), 512, 0, stream>>>(x1b, W1T, b1, hbuf, ROWSz, 2048, 512);
  gemm_bt<64, 64, 4><<<dim3(4, 128), 256, 0, stream>>>(hbuf, W2T, b2, nullptr, x1b, nullptr, y2, ROWSz, 512, 2048);
  layer_norm_k<1><<<dim3(2048), 256, 0, stream>>>(y2, g2, be2, d_out);
}